// Round 1
// baseline (759.511 us; speedup 1.0000x reference)
//
#include <hip/hip_runtime.h>
#include <math.h>

#define HEADS 8
#define NEG 0.2f

// ---------------- utility: zero a word region ----------------
__global__ void zero_k(int* __restrict__ p, int n) {
  int i = blockIdx.x * blockDim.x + threadIdx.x;
  int stride = gridDim.x * blockDim.x;
  for (; i < n; i += stride) p[i] = 0;
}

// ---------------- edge prep: append self loops ----------------
__global__ void prep_k(const int* __restrict__ ei, int* __restrict__ src,
                       int* __restrict__ dst, int E, int Nn) {
  int i = blockIdx.x * blockDim.x + threadIdx.x;
  int tot = E + Nn;
  if (i >= tot) return;
  if (i < E) { src[i] = ei[i]; dst[i] = ei[E + i]; }
  else       { src[i] = i - E; dst[i] = i - E; }
}

__global__ void count_k(const int* __restrict__ dst, int* __restrict__ deg, int Etot) {
  int i = blockIdx.x * blockDim.x + threadIdx.x;
  if (i < Etot) atomicAdd(&deg[dst[i]], 1);
}

// single-block Hillis-Steele scan over N (chunked by 1024)
__global__ __launch_bounds__(1024) void scan_k(const int* __restrict__ deg,
                                               int* __restrict__ offs,
                                               int* __restrict__ cursor, int Nn) {
  __shared__ int sdata[1024];
  __shared__ int soff;
  int t = threadIdx.x;
  if (t == 0) soff = 0;
  __syncthreads();
  for (int base = 0; base < Nn; base += 1024) {
    int v = (base + t < Nn) ? deg[base + t] : 0;
    sdata[t] = v;
    __syncthreads();
    for (int o = 1; o < 1024; o <<= 1) {
      int x = (t >= o) ? sdata[t - o] : 0;
      __syncthreads();
      sdata[t] += x;
      __syncthreads();
    }
    int inc = sdata[t];
    int total = sdata[1023];
    int excl = soff + inc - v;
    if (base + t < Nn) { offs[base + t] = excl; cursor[base + t] = excl; }
    __syncthreads();
    if (t == 0) soff += total;
    __syncthreads();
  }
  if (t == 0) offs[Nn] = soff;
}

__global__ void scatter_k(const int* __restrict__ dst, int* __restrict__ cursor,
                          int* __restrict__ perm, int Etot) {
  int i = blockIdx.x * blockDim.x + threadIdx.x;
  if (i < Etot) { int p = atomicAdd(&cursor[dst[i]], 1); perm[p] = i; }
}

// ---------------- fp32 tiled GEMM: C[M,N] = A[M,K] @ B[K,N] ----------------
// 64x64 tile, 256 threads, 4x4 per thread, K-chunks of 16.
// N % 64 == 0 and K % 16 == 0 assumed (holds: N=1024/512, K=128/1024).
__global__ __launch_bounds__(256) void sgemm_k(const float* __restrict__ A,
                                               const float* __restrict__ B,
                                               float* __restrict__ C,
                                               int M, int N, int K) {
  __shared__ float As[16 * 68];  // [k][m], padded 64->68 (16B-aligned rows, conflict-free)
  __shared__ float Bs[16 * 64];  // [k][n]
  int bm = blockIdx.y * 64, bn = blockIdx.x * 64;
  int tid = threadIdx.x;
  int tm = (tid >> 4) << 2;
  int tn = (tid & 15) << 2;
  float acc[4][4] = {};
  for (int k0 = 0; k0 < K; k0 += 16) {
#pragma unroll
    for (int i = 0; i < 4; i++) {
      int idx = tid + i * 256;
      int k = idx & 15, m = idx >> 4;
      int gm = bm + m;
      As[k * 68 + m] = (gm < M) ? A[(size_t)gm * K + k0 + k] : 0.f;
    }
#pragma unroll
    for (int i = 0; i < 4; i++) {
      int idx = tid + i * 256;
      int k = idx >> 6, n = idx & 63;
      Bs[k * 64 + n] = B[(size_t)(k0 + k) * N + bn + n];
    }
    __syncthreads();
#pragma unroll
    for (int k = 0; k < 16; k++) {
      float4 av = *(const float4*)&As[k * 68 + tm];
      float4 bv = *(const float4*)&Bs[k * 64 + tn];
      float a[4] = {av.x, av.y, av.z, av.w};
      float b[4] = {bv.x, bv.y, bv.z, bv.w};
#pragma unroll
      for (int i = 0; i < 4; i++)
#pragma unroll
        for (int j = 0; j < 4; j++) acc[i][j] += a[i] * b[j];
    }
    __syncthreads();
  }
#pragma unroll
  for (int i = 0; i < 4; i++) {
    int gm = bm + tm + i;
    if (gm < M) {
      float4 v = make_float4(acc[i][0], acc[i][1], acc[i][2], acc[i][3]);
      *(float4*)&C[(size_t)gm * N + bn + tn] = v;
    }
  }
}

// ---------------- alpha_src / alpha_dst: one wave per (n,h) ----------------
template <int C>
__global__ __launch_bounds__(256) void alpha_k(const float* __restrict__ h,
                                               const float* __restrict__ att_s,
                                               const float* __restrict__ att_d,
                                               float* __restrict__ osrc,
                                               float* __restrict__ odst, int NH) {
  int wid = (blockIdx.x * 256 + threadIdx.x) >> 6;
  int lane = threadIdx.x & 63;
  if (wid >= NH) return;
  int hh = wid & (HEADS - 1);
  const float* row = h + (size_t)wid * C;
  const float* ar = att_s + hh * C;
  const float* br = att_d + hh * C;
  float s = 0.f, d = 0.f;
#pragma unroll
  for (int c = lane; c < C; c += 64) {
    float v = row[c];
    s += v * ar[c];
    d += v * br[c];
  }
#pragma unroll
  for (int o = 32; o > 0; o >>= 1) {
    s += __shfl_down(s, o);
    d += __shfl_down(d, o);
  }
  if (lane == 0) { osrc[wid] = s; odst[wid] = d; }
}

// ---------------- edge logits -> exp, denom accumulation ----------------
__global__ void edge_k(const int* __restrict__ src, const int* __restrict__ dst,
                       const float* __restrict__ asrc, const float* __restrict__ adst,
                       float* __restrict__ ex, float* __restrict__ denom, int Etot) {
  int i = blockIdx.x * blockDim.x + threadIdx.x;
  if (i >= Etot * HEADS) return;
  int e = i >> 3, hh = i & 7;
  float v = asrc[src[e] * HEADS + hh] + adst[dst[e] * HEADS + hh];
  v = (v > 0.f) ? v : NEG * v;   // leaky_relu(0.2)
  float ev = expf(v);            // softmax is shift-invariant; |v| small -> no max needed
  ex[i] = ev;
  atomicAdd(&denom[dst[e] * HEADS + hh], ev);
}

// ---------------- CSR aggregation + bias + ELU ----------------
// block per node, thread t owns channels t + j*256; F = 256*REGS; head = c >> CSHIFT
template <int CSHIFT, int REGS>
__global__ __launch_bounds__(256) void aggregate_k(const float* __restrict__ h,
                                                   const float* __restrict__ ex,
                                                   const float* __restrict__ denom,
                                                   const int* __restrict__ offs,
                                                   const int* __restrict__ perm,
                                                   const int* __restrict__ src,
                                                   const float* __restrict__ bias,
                                                   float* __restrict__ out) {
  const int F = 256 * REGS;
  int n = blockIdx.x;
  int t = threadIdx.x;
  float acc[REGS] = {};
  int hh[REGS];
#pragma unroll
  for (int j = 0; j < REGS; j++) hh[j] = (t + j * 256) >> CSHIFT;
  int e0 = offs[n], e1 = offs[n + 1];
  for (int i = e0; i < e1; i++) {
    int e = perm[i];
    int s = src[e];
    const float* row = h + (size_t)s * F;
#pragma unroll
    for (int j = 0; j < REGS; j++) acc[j] += ex[e * HEADS + hh[j]] * row[t + j * 256];
  }
#pragma unroll
  for (int j = 0; j < REGS; j++) {
    int c = t + j * 256;
    float v = acc[j] / denom[n * HEADS + hh[j]] + bias[c];
    out[(size_t)n * F + c] = (v > 0.f) ? v : expm1f(v);  // ELU
  }
}

// ---------------- batch counts & pooled sums ----------------
__global__ void cnt_k(const int* __restrict__ batch, int* __restrict__ cnt, int Nn) {
  int i = blockIdx.x * blockDim.x + threadIdx.x;
  if (i < Nn) atomicAdd(&cnt[batch[i]], 1);
}

__global__ __launch_bounds__(256) void pool_k(const float* __restrict__ g,
                                              const int* __restrict__ batch,
                                              float* __restrict__ sums, int Nn) {
  int c = blockIdx.x * 256 + threadIdx.x;  // 0..511
  int n0 = blockIdx.y * 250;
  int n1 = min(n0 + 250, Nn);
  if (n0 >= n1) return;
  float acc = 0.f;
  int cur = batch[n0];
  for (int n = n0; n < n1; n++) {
    int b = batch[n];
    if (b != cur) { atomicAdd(&sums[cur * 512 + c], acc); acc = 0.f; cur = b; }
    acc += g[(size_t)n * 512 + c];
  }
  atomicAdd(&sums[cur * 512 + c], acc);
}

// ---------------- mean + fc1(elu) + fc2, one block ----------------
__global__ __launch_bounds__(512) void mlp_k(const float* __restrict__ sums,
                                             const int* __restrict__ cnt,
                                             const float* __restrict__ w1,
                                             const float* __restrict__ b1,
                                             const float* __restrict__ w2,
                                             const float* __restrict__ b2,
                                             float* __restrict__ out) {
  __shared__ float gm[16 * 512];
  __shared__ float t1[16 * 32];
  int t = threadIdx.x;
  for (int i = t; i < 16 * 512; i += 512) {
    int b = i >> 9;
    gm[i] = sums[i] / fmaxf((float)cnt[b], 1.f);
  }
  __syncthreads();
  {
    int b = t >> 5, j = t & 31;
    float s = b1[j];
    for (int k = 0; k < 512; k++) s += gm[(b << 9) + k] * w1[k * 32 + j];
    t1[t] = (s > 0.f) ? s : expm1f(s);
  }
  __syncthreads();
  if (t < 160) {
    int b = t / 10, j = t - b * 10;
    float s = b2[j];
#pragma unroll
    for (int k = 0; k < 32; k++) s += t1[b * 32 + k] * w2[k * 10 + j];
    out[t] = s;
  }
}

extern "C" void kernel_launch(void* const* d_in, const int* in_sizes, int n_in,
                              void* d_out, int out_size, void* d_ws, size_t ws_size,
                              hipStream_t stream) {
  const float* x   = (const float*)d_in[0];
  const int*   ei  = (const int*)d_in[1];
  const int* batch = (const int*)d_in[2];
  const float* W1  = (const float*)d_in[3];
  const float* as1 = (const float*)d_in[4];
  const float* ad1 = (const float*)d_in[5];
  const float* b1  = (const float*)d_in[6];
  const float* W2  = (const float*)d_in[7];
  const float* as2 = (const float*)d_in[8];
  const float* ad2 = (const float*)d_in[9];
  const float* b2  = (const float*)d_in[10];
  const float* f1w = (const float*)d_in[11];
  const float* f1b = (const float*)d_in[12];
  const float* f2w = (const float*)d_in[13];
  const float* f2b = (const float*)d_in[14];
  float* out = (float*)d_out;

  const int Nn = in_sizes[2];      // 10000
  const int E = in_sizes[1] / 2;   // 160000
  const int Etot = E + Nn;         // self loops appended

  // ---- workspace layout (4B words, 64-word aligned) ----
  size_t off = 0;
  auto alloc = [&](size_t elems) { size_t o = off; off += (elems + 63) & ~(size_t)63; return o; };
  int* wsi = (int*)d_ws;
  float* wsf = (float*)d_ws;

  size_t o_deg  = alloc(Nn);
  size_t o_den1 = alloc((size_t)Nn * 8);
  size_t o_den2 = alloc((size_t)Nn * 8);
  size_t o_pool = alloc(16 * 512);
  size_t o_cnt  = alloc(64);
  size_t zero_words = off;               // everything above is accumulated into -> zero each call
  size_t o_offs = alloc(Nn + 1);
  size_t o_cur  = alloc(Nn);
  size_t o_src  = alloc(Etot);
  size_t o_dst  = alloc(Etot);
  size_t o_perm = alloc(Etot);
  size_t o_asrc = alloc((size_t)Nn * 8);
  size_t o_adst = alloc((size_t)Nn * 8);
  size_t o_ex   = alloc((size_t)Etot * 8);
  size_t o_h    = alloc((size_t)Nn * 1024);  // h1, reused as h2
  size_t o_g    = alloc((size_t)Nn * 1024);  // g1, reused as g2

  int eb = (Etot + 255) / 256;

  zero_k<<<512, 256, 0, stream>>>(wsi, (int)zero_words);
  prep_k<<<eb, 256, 0, stream>>>(ei, wsi + o_src, wsi + o_dst, E, Nn);
  count_k<<<eb, 256, 0, stream>>>(wsi + o_dst, wsi + o_deg, Etot);
  scan_k<<<1, 1024, 0, stream>>>(wsi + o_deg, wsi + o_offs, wsi + o_cur, Nn);
  scatter_k<<<eb, 256, 0, stream>>>(wsi + o_dst, wsi + o_cur, wsi + o_perm, Etot);

  // ---- layer 1: 128 -> 8x128 ----
  sgemm_k<<<dim3(1024 / 64, (Nn + 63) / 64), 256, 0, stream>>>(x, W1, wsf + o_h, Nn, 1024, 128);
  alpha_k<128><<<(Nn * 8) / 4, 256, 0, stream>>>(wsf + o_h, as1, ad1, wsf + o_asrc, wsf + o_adst, Nn * 8);
  edge_k<<<(Etot * 8 + 255) / 256, 256, 0, stream>>>(wsi + o_src, wsi + o_dst, wsf + o_asrc,
                                                     wsf + o_adst, wsf + o_ex, wsf + o_den1, Etot);
  aggregate_k<7, 4><<<Nn, 256, 0, stream>>>(wsf + o_h, wsf + o_ex, wsf + o_den1, wsi + o_offs,
                                            wsi + o_perm, wsi + o_src, b1, wsf + o_g);

  // ---- layer 2: 1024 -> 8x64 ----
  sgemm_k<<<dim3(512 / 64, (Nn + 63) / 64), 256, 0, stream>>>(wsf + o_g, W2, wsf + o_h, Nn, 512, 1024);
  alpha_k<64><<<(Nn * 8) / 4, 256, 0, stream>>>(wsf + o_h, as2, ad2, wsf + o_asrc, wsf + o_adst, Nn * 8);
  edge_k<<<(Etot * 8 + 255) / 256, 256, 0, stream>>>(wsi + o_src, wsi + o_dst, wsf + o_asrc,
                                                     wsf + o_adst, wsf + o_ex, wsf + o_den2, Etot);
  aggregate_k<6, 2><<<Nn, 256, 0, stream>>>(wsf + o_h, wsf + o_ex, wsf + o_den2, wsi + o_offs,
                                            wsi + o_perm, wsi + o_src, b2, wsf + o_g);

  // ---- pool + MLP ----
  cnt_k<<<(Nn + 255) / 256, 256, 0, stream>>>(batch, wsi + o_cnt, Nn);
  pool_k<<<dim3(2, (Nn + 249) / 250), 256, 0, stream>>>(wsf + o_g, batch, wsf + o_pool, Nn);
  mlp_k<<<1, 512, 0, stream>>>(wsf + o_pool, wsi + o_cnt, f1w, f1b, f2w, f2b, out);
}

// Round 2
// 602.956 us; speedup vs baseline: 1.2596x; 1.2596x over previous
//
#include <hip/hip_runtime.h>
#include <math.h>

#define HEADS 8
#define NEG 0.2f

typedef unsigned short ushort_t;
typedef __attribute__((ext_vector_type(8))) short short8;
typedef float f32x4 __attribute__((ext_vector_type(4)));

__device__ inline ushort_t f2bf(float f) {
  union { float f; unsigned u; } v; v.f = f;
  unsigned r = (v.u + 0x7FFF + ((v.u >> 16) & 1)) >> 16;  // RNE
  return (ushort_t)r;
}

// ---------------- utility: zero a word region ----------------
__global__ void zero_k(int* __restrict__ p, int n) {
  int i = blockIdx.x * blockDim.x + threadIdx.x;
  int stride = gridDim.x * blockDim.x;
  for (; i < n; i += stride) p[i] = 0;
}

// ---------------- edge prep: append self loops ----------------
__global__ void prep_k(const int* __restrict__ ei, int* __restrict__ src,
                       int* __restrict__ dst, int E, int Nn) {
  int i = blockIdx.x * blockDim.x + threadIdx.x;
  int tot = E + Nn;
  if (i >= tot) return;
  if (i < E) { src[i] = ei[i]; dst[i] = ei[E + i]; }
  else       { src[i] = i - E; dst[i] = i - E; }
}

__global__ void count_k(const int* __restrict__ dst, int* __restrict__ deg, int Etot) {
  int i = blockIdx.x * blockDim.x + threadIdx.x;
  if (i < Etot) atomicAdd(&deg[dst[i]], 1);
}

// single-block Hillis-Steele scan over N (chunked by 1024)
__global__ __launch_bounds__(1024) void scan_k(const int* __restrict__ deg,
                                               int* __restrict__ offs,
                                               int* __restrict__ cursor, int Nn) {
  __shared__ int sdata[1024];
  __shared__ int soff;
  int t = threadIdx.x;
  if (t == 0) soff = 0;
  __syncthreads();
  for (int base = 0; base < Nn; base += 1024) {
    int v = (base + t < Nn) ? deg[base + t] : 0;
    sdata[t] = v;
    __syncthreads();
    for (int o = 1; o < 1024; o <<= 1) {
      int x = (t >= o) ? sdata[t - o] : 0;
      __syncthreads();
      sdata[t] += x;
      __syncthreads();
    }
    int inc = sdata[t];
    int total = sdata[1023];
    int excl = soff + inc - v;
    if (base + t < Nn) { offs[base + t] = excl; cursor[base + t] = excl; }
    __syncthreads();
    if (t == 0) soff += total;
    __syncthreads();
  }
  if (t == 0) offs[Nn] = soff;
}

__global__ void scatter_k(const int* __restrict__ dst, int* __restrict__ cursor,
                          int* __restrict__ perm, int Etot) {
  int i = blockIdx.x * blockDim.x + threadIdx.x;
  if (i < Etot) { int p = atomicAdd(&cursor[dst[i]], 1); perm[p] = i; }
}

// ---------------- casts ----------------
__global__ void cast_k(const float* __restrict__ in, ushort_t* __restrict__ out, int n4) {
  int i = blockIdx.x * blockDim.x + threadIdx.x;
  if (i >= n4) return;
  float4 v = ((const float4*)in)[i];
  ushort_t o[4] = {f2bf(v.x), f2bf(v.y), f2bf(v.z), f2bf(v.w)};
  *(uint2*)&out[i * 4] = *(uint2*)o;
}

// W [K][N] fp32 -> Wt [N][K] bf16 (coalesced writes)
__global__ void tcast_k(const float* __restrict__ W, ushort_t* __restrict__ Wt, int K, int N) {
  int idx = blockIdx.x * blockDim.x + threadIdx.x;
  if (idx >= K * N) return;
  int n = idx / K, k = idx - n * K;
  Wt[idx] = f2bf(W[(size_t)k * N + n]);
}

// ---------------- bf16 MFMA GEMM: C[M,N] = A[M,K] @ Bt[N,K]^T ----------------
// 128x128 tile, 256 threads (4 waves in 2x2), BK=32, 16x16x32 MFMA, fp32 out.
// N % 128 == 0, K % 32 == 0 assumed (N=1024/512, K=128/1024).
#define LDA 40  // padded LDS row stride (bf16 elems); 80B keeps 16B align, ~2-way banks
__global__ __launch_bounds__(256) void mfma_gemm_k(const ushort_t* __restrict__ A,
                                                   const ushort_t* __restrict__ Bt,
                                                   float* __restrict__ C,
                                                   int M, int N, int K) {
  __shared__ ushort_t As[128 * LDA];
  __shared__ ushort_t Bs[128 * LDA];
  int tid = threadIdx.x;
  int lane = tid & 63;
  int wave = tid >> 6;
  int wm = (wave >> 1) * 64, wn = (wave & 1) * 64;
  int bm = blockIdx.y * 128, bn = blockIdx.x * 128;
  int lrow = lane & 15, lq = lane >> 4;

  f32x4 acc[4][4];
#pragma unroll
  for (int i = 0; i < 4; i++)
#pragma unroll
    for (int j = 0; j < 4; j++) acc[i][j] = 0.f;

  int srow = tid >> 2;          // 0..63
  int skc = (tid & 3) * 8;      // k elem offset within BK

  for (int k0 = 0; k0 < K; k0 += 32) {
    int gr0 = min(bm + srow, M - 1);
    int gr1 = min(bm + srow + 64, M - 1);
    short8 va0 = *(const short8*)&A[(size_t)gr0 * K + k0 + skc];
    short8 va1 = *(const short8*)&A[(size_t)gr1 * K + k0 + skc];
    short8 vb0 = *(const short8*)&Bt[(size_t)(bn + srow) * K + k0 + skc];
    short8 vb1 = *(const short8*)&Bt[(size_t)(bn + srow + 64) * K + k0 + skc];
    __syncthreads();  // previous iter's fragment reads done before overwrite
    *(short8*)&As[srow * LDA + skc] = va0;
    *(short8*)&As[(srow + 64) * LDA + skc] = va1;
    *(short8*)&Bs[srow * LDA + skc] = vb0;
    *(short8*)&Bs[(srow + 64) * LDA + skc] = vb1;
    __syncthreads();
    short8 af[4], bfr[4];
#pragma unroll
    for (int t = 0; t < 4; t++) {
      af[t]  = *(const short8*)&As[(wm + t * 16 + lrow) * LDA + lq * 8];
      bfr[t] = *(const short8*)&Bs[(wn + t * 16 + lrow) * LDA + lq * 8];
    }
#pragma unroll
    for (int i = 0; i < 4; i++)
#pragma unroll
      for (int j = 0; j < 4; j++)
        acc[i][j] = __builtin_amdgcn_mfma_f32_16x16x32_bf16(af[i], bfr[j], acc[i][j], 0, 0, 0);
  }

#pragma unroll
  for (int i = 0; i < 4; i++) {
    int row0 = bm + wm + i * 16 + lq * 4;  // C/D: col=lane&15, row=(lane>>4)*4+reg
#pragma unroll
    for (int j = 0; j < 4; j++) {
      int col = bn + wn + j * 16 + lrow;
#pragma unroll
      for (int r = 0; r < 4; r++) {
        int row = row0 + r;
        if (row < M) C[(size_t)row * N + col] = acc[i][j][r];
      }
    }
  }
}

// ---------------- alpha_src / alpha_dst: one wave per (n,h) ----------------
template <int C>
__global__ __launch_bounds__(256) void alpha_k(const float* __restrict__ h,
                                               const float* __restrict__ att_s,
                                               const float* __restrict__ att_d,
                                               float* __restrict__ osrc,
                                               float* __restrict__ odst, int NH) {
  int wid = (blockIdx.x * 256 + threadIdx.x) >> 6;
  int lane = threadIdx.x & 63;
  if (wid >= NH) return;
  int hh = wid & (HEADS - 1);
  const float* row = h + (size_t)wid * C;
  const float* ar = att_s + hh * C;
  const float* br = att_d + hh * C;
  float s = 0.f, d = 0.f;
#pragma unroll
  for (int c = lane; c < C; c += 64) {
    float v = row[c];
    s += v * ar[c];
    d += v * br[c];
  }
#pragma unroll
  for (int o = 32; o > 0; o >>= 1) {
    s += __shfl_down(s, o);
    d += __shfl_down(d, o);
  }
  if (lane == 0) { osrc[wid] = s; odst[wid] = d; }
}

// ---------------- edge logits -> exp, denom accumulation ----------------
__global__ void edge_k(const int* __restrict__ src, const int* __restrict__ dst,
                       const float* __restrict__ asrc, const float* __restrict__ adst,
                       float* __restrict__ ex, float* __restrict__ denom, int Etot) {
  int i = blockIdx.x * blockDim.x + threadIdx.x;
  if (i >= Etot * HEADS) return;
  int e = i >> 3, hh = i & 7;
  float v = asrc[src[e] * HEADS + hh] + adst[dst[e] * HEADS + hh];
  v = (v > 0.f) ? v : NEG * v;   // leaky_relu(0.2)
  float ev = expf(v);            // softmax is shift-invariant; |v| small -> no max needed
  ex[i] = ev;
  atomicAdd(&denom[dst[e] * HEADS + hh], ev);
}

// ---------------- CSR aggregation + bias + ELU ----------------
// block per node, thread t owns channels t + j*256; F = 256*REGS; head = c >> CSHIFT
// OT = float (fp32 out) or ushort_t (bf16 out, feeds next GEMM)
template <int CSHIFT, int REGS, typename OT>
__global__ __launch_bounds__(256) void aggregate_k(const float* __restrict__ h,
                                                   const float* __restrict__ ex,
                                                   const float* __restrict__ denom,
                                                   const int* __restrict__ offs,
                                                   const int* __restrict__ perm,
                                                   const int* __restrict__ src,
                                                   const float* __restrict__ bias,
                                                   OT* __restrict__ out) {
  const int F = 256 * REGS;
  int n = blockIdx.x;
  int t = threadIdx.x;
  float acc[REGS] = {};
  int hh[REGS];
#pragma unroll
  for (int j = 0; j < REGS; j++) hh[j] = (t + j * 256) >> CSHIFT;
  int e0 = offs[n], e1 = offs[n + 1];
  for (int i = e0; i < e1; i++) {
    int e = perm[i];
    int s = src[e];
    const float* row = h + (size_t)s * F;
#pragma unroll
    for (int j = 0; j < REGS; j++) acc[j] += ex[e * HEADS + hh[j]] * row[t + j * 256];
  }
#pragma unroll
  for (int j = 0; j < REGS; j++) {
    int c = t + j * 256;
    float v = acc[j] / denom[n * HEADS + hh[j]] + bias[c];
    v = (v > 0.f) ? v : expm1f(v);  // ELU
    if (sizeof(OT) == 2) ((ushort_t*)out)[(size_t)n * F + c] = f2bf(v);
    else ((float*)out)[(size_t)n * F + c] = v;
  }
}

// ---------------- batch counts & pooled sums ----------------
__global__ void cnt_k(const int* __restrict__ batch, int* __restrict__ cnt, int Nn) {
  int i = blockIdx.x * blockDim.x + threadIdx.x;
  if (i < Nn) atomicAdd(&cnt[batch[i]], 1);
}

__global__ __launch_bounds__(256) void pool_k(const float* __restrict__ g,
                                              const int* __restrict__ batch,
                                              float* __restrict__ sums, int Nn) {
  int c = blockIdx.x * 256 + threadIdx.x;  // 0..511
  int n0 = blockIdx.y * 250;
  int n1 = min(n0 + 250, Nn);
  if (n0 >= n1) return;
  float acc = 0.f;
  int cur = batch[n0];
  for (int n = n0; n < n1; n++) {
    int b = batch[n];
    if (b != cur) { atomicAdd(&sums[cur * 512 + c], acc); acc = 0.f; cur = b; }
    acc += g[(size_t)n * 512 + c];
  }
  atomicAdd(&sums[cur * 512 + c], acc);
}

// ---------------- mean + fc1(elu) + fc2, one block ----------------
__global__ __launch_bounds__(512) void mlp_k(const float* __restrict__ sums,
                                             const int* __restrict__ cnt,
                                             const float* __restrict__ w1,
                                             const float* __restrict__ b1,
                                             const float* __restrict__ w2,
                                             const float* __restrict__ b2,
                                             float* __restrict__ out) {
  __shared__ float gm[16 * 512];
  __shared__ float t1[16 * 32];
  int t = threadIdx.x;
  for (int i = t; i < 16 * 512; i += 512) {
    int b = i >> 9;
    gm[i] = sums[i] / fmaxf((float)cnt[b], 1.f);
  }
  __syncthreads();
  {
    int b = t >> 5, j = t & 31;
    float s = b1[j];
    for (int k = 0; k < 512; k++) s += gm[(b << 9) + k] * w1[k * 32 + j];
    t1[t] = (s > 0.f) ? s : expm1f(s);
  }
  __syncthreads();
  if (t < 160) {
    int b = t / 10, j = t - b * 10;
    float s = b2[j];
#pragma unroll
    for (int k = 0; k < 32; k++) s += t1[b * 32 + k] * w2[k * 10 + j];
    out[t] = s;
  }
}

extern "C" void kernel_launch(void* const* d_in, const int* in_sizes, int n_in,
                              void* d_out, int out_size, void* d_ws, size_t ws_size,
                              hipStream_t stream) {
  const float* x   = (const float*)d_in[0];
  const int*   ei  = (const int*)d_in[1];
  const int* batch = (const int*)d_in[2];
  const float* W1  = (const float*)d_in[3];
  const float* as1 = (const float*)d_in[4];
  const float* ad1 = (const float*)d_in[5];
  const float* b1  = (const float*)d_in[6];
  const float* W2  = (const float*)d_in[7];
  const float* as2 = (const float*)d_in[8];
  const float* ad2 = (const float*)d_in[9];
  const float* b2  = (const float*)d_in[10];
  const float* f1w = (const float*)d_in[11];
  const float* f1b = (const float*)d_in[12];
  const float* f2w = (const float*)d_in[13];
  const float* f2b = (const float*)d_in[14];
  float* out = (float*)d_out;

  const int Nn = in_sizes[2];      // 10000
  const int E = in_sizes[1] / 2;   // 160000
  const int Etot = E + Nn;         // self loops appended

  // ---- workspace layout (4B words, 64-word aligned) ----
  size_t off = 0;
  auto alloc = [&](size_t elems) { size_t o = off; off += (elems + 63) & ~(size_t)63; return o; };
  int* wsi = (int*)d_ws;
  float* wsf = (float*)d_ws;

  size_t o_deg  = alloc(Nn);
  size_t o_den1 = alloc((size_t)Nn * 8);
  size_t o_den2 = alloc((size_t)Nn * 8);
  size_t o_pool = alloc(16 * 512);
  size_t o_cnt  = alloc(64);
  size_t zero_words = off;               // everything above is accumulated into -> zero each call
  size_t o_offs = alloc(Nn + 1);
  size_t o_cur  = alloc(Nn);
  size_t o_src  = alloc(Etot);
  size_t o_dst  = alloc(Etot);
  size_t o_perm = alloc(Etot);
  size_t o_asrc = alloc((size_t)Nn * 8);
  size_t o_adst = alloc((size_t)Nn * 8);
  size_t o_ex   = alloc((size_t)Etot * 8);
  size_t o_xb   = alloc((size_t)Nn * 128 / 2);   // x bf16  [N,128]
  size_t o_w1t  = alloc(1024 * 128 / 2);         // W1^T bf16 [1024,128]
  size_t o_w2t  = alloc(512 * 1024 / 2);         // W2^T bf16 [512,1024]
  size_t o_h    = alloc((size_t)Nn * 1024);      // h1 fp32, reused as h2
  size_t o_g    = alloc((size_t)Nn * 1024);      // g1 bf16 (first half), then g2 fp32

  ushort_t* xb  = (ushort_t*)(wsi + o_xb);
  ushort_t* w1t = (ushort_t*)(wsi + o_w1t);
  ushort_t* w2t = (ushort_t*)(wsi + o_w2t);
  ushort_t* g1b = (ushort_t*)(wsi + o_g);

  int eb = (Etot + 255) / 256;

  zero_k<<<512, 256, 0, stream>>>(wsi, (int)zero_words);
  prep_k<<<eb, 256, 0, stream>>>(ei, wsi + o_src, wsi + o_dst, E, Nn);
  count_k<<<eb, 256, 0, stream>>>(wsi + o_dst, wsi + o_deg, Etot);
  scan_k<<<1, 1024, 0, stream>>>(wsi + o_deg, wsi + o_offs, wsi + o_cur, Nn);
  scatter_k<<<eb, 256, 0, stream>>>(wsi + o_dst, wsi + o_cur, wsi + o_perm, Etot);

  // ---- casts for MFMA ----
  cast_k<<<(Nn * 128 / 4 + 255) / 256, 256, 0, stream>>>(x, xb, Nn * 128 / 4);
  tcast_k<<<(128 * 1024 + 255) / 256, 256, 0, stream>>>(W1, w1t, 128, 1024);
  tcast_k<<<(1024 * 512 + 255) / 256, 256, 0, stream>>>(W2, w2t, 1024, 512);

  // ---- layer 1: 128 -> 8x128 ----
  mfma_gemm_k<<<dim3(1024 / 128, (Nn + 127) / 128), 256, 0, stream>>>(xb, w1t, wsf + o_h, Nn, 1024, 128);
  alpha_k<128><<<(Nn * 8) / 4, 256, 0, stream>>>(wsf + o_h, as1, ad1, wsf + o_asrc, wsf + o_adst, Nn * 8);
  edge_k<<<(Etot * 8 + 255) / 256, 256, 0, stream>>>(wsi + o_src, wsi + o_dst, wsf + o_asrc,
                                                     wsf + o_adst, wsf + o_ex, wsf + o_den1, Etot);
  aggregate_k<7, 4, ushort_t><<<Nn, 256, 0, stream>>>(wsf + o_h, wsf + o_ex, wsf + o_den1, wsi + o_offs,
                                                      wsi + o_perm, wsi + o_src, b1, g1b);

  // ---- layer 2: 1024 -> 8x64 ----
  mfma_gemm_k<<<dim3(512 / 128, (Nn + 127) / 128), 256, 0, stream>>>(g1b, w2t, wsf + o_h, Nn, 512, 1024);
  alpha_k<64><<<(Nn * 8) / 4, 256, 0, stream>>>(wsf + o_h, as2, ad2, wsf + o_asrc, wsf + o_adst, Nn * 8);
  edge_k<<<(Etot * 8 + 255) / 256, 256, 0, stream>>>(wsi + o_src, wsi + o_dst, wsf + o_asrc,
                                                     wsf + o_adst, wsf + o_ex, wsf + o_den2, Etot);
  aggregate_k<6, 2, float><<<Nn, 256, 0, stream>>>(wsf + o_h, wsf + o_ex, wsf + o_den2, wsi + o_offs,
                                                   wsi + o_perm, wsi + o_src, b2, wsf + o_g);

  // ---- pool + MLP ----
  cnt_k<<<(Nn + 255) / 256, 256, 0, stream>>>(batch, wsi + o_cnt, Nn);
  pool_k<<<dim3(2, (Nn + 249) / 250), 256, 0, stream>>>(wsf + o_g, batch, wsf + o_pool, Nn);
  mlp_k<<<1, 512, 0, stream>>>(wsf + o_pool, wsi + o_cnt, f1w, f1b, f2w, f2b, out);
}

// Round 3
// 482.494 us; speedup vs baseline: 1.5741x; 1.2497x over previous
//
#include <hip/hip_runtime.h>
#include <math.h>

#define HEADS 8
#define NEG 0.2f

typedef unsigned short ushort_t;
typedef __attribute__((ext_vector_type(8))) short short8;
typedef float f32x4 __attribute__((ext_vector_type(4)));

__device__ inline ushort_t f2bf(float f) {
  union { float f; unsigned u; } v; v.f = f;
  unsigned r = (v.u + 0x7FFF + ((v.u >> 16) & 1)) >> 16;  // RNE
  return (ushort_t)r;
}

// ---------------- utility: zero a word region ----------------
__global__ void zero_k(int* __restrict__ p, int n) {
  int i = blockIdx.x * blockDim.x + threadIdx.x;
  int stride = gridDim.x * blockDim.x;
  for (; i < n; i += stride) p[i] = 0;
}

// ---------------- edge prep: append self loops ----------------
__global__ void prep_k(const int* __restrict__ ei, int* __restrict__ src,
                       int* __restrict__ dst, int E, int Nn) {
  int i = blockIdx.x * blockDim.x + threadIdx.x;
  int tot = E + Nn;
  if (i >= tot) return;
  if (i < E) { src[i] = ei[i]; dst[i] = ei[E + i]; }
  else       { src[i] = i - E; dst[i] = i - E; }
}

__global__ void count_k(const int* __restrict__ dst, int* __restrict__ deg, int Etot) {
  int i = blockIdx.x * blockDim.x + threadIdx.x;
  if (i < Etot) atomicAdd(&deg[dst[i]], 1);
}

// single-block scan over N, wave-shuffle based (2 barriers per 1024-chunk)
__global__ __launch_bounds__(1024) void scan_k(const int* __restrict__ deg,
                                               int* __restrict__ offs,
                                               int* __restrict__ cursor, int Nn) {
  __shared__ int wtot[16];
  __shared__ int wexcl[16];
  __shared__ int soff_s;
  int t = threadIdx.x;
  int lane = t & 63, w = t >> 6;
  if (t == 0) soff_s = 0;
  __syncthreads();
  for (int base = 0; base < Nn; base += 1024) {
    int v = (base + t < Nn) ? deg[base + t] : 0;
    int sc = v;
#pragma unroll
    for (int o = 1; o < 64; o <<= 1) {
      int x = __shfl_up(sc, o);
      if (lane >= o) sc += x;
    }
    if (lane == 63) wtot[w] = sc;
    __syncthreads();
    if (w == 0) {
      int tv = (lane < 16) ? wtot[lane] : 0;
      int ts = tv;
#pragma unroll
      for (int o = 1; o < 16; o <<= 1) {
        int x = __shfl_up(ts, o);
        if (lane >= o) ts += x;
      }
      if (lane < 16) wexcl[lane] = ts - tv;
      if (lane == 15) wtot[15] = ts;  // chunk total
    }
    __syncthreads();
    int soff = soff_s;
    int excl = soff + wexcl[w] + sc - v;
    if (base + t < Nn) { offs[base + t] = excl; cursor[base + t] = excl; }
    int chunk_total = wtot[15];
    __syncthreads();
    if (t == 0) soff_s = soff + chunk_total;
    __syncthreads();
  }
  if (t == 0) offs[Nn] = soff_s;
}

__global__ void scatter_k(const int* __restrict__ dst, int* __restrict__ cursor,
                          int* __restrict__ perm, int Etot) {
  int i = blockIdx.x * blockDim.x + threadIdx.x;
  if (i < Etot) { int p = atomicAdd(&cursor[dst[i]], 1); perm[p] = i; }
}

// ---------------- casts ----------------
__global__ void cast_k(const float* __restrict__ in, ushort_t* __restrict__ out, int n4) {
  int i = blockIdx.x * blockDim.x + threadIdx.x;
  if (i >= n4) return;
  float4 v = ((const float4*)in)[i];
  ushort_t o[4] = {f2bf(v.x), f2bf(v.y), f2bf(v.z), f2bf(v.w)};
  *(uint2*)&out[i * 4] = *(uint2*)o;
}

// W [K][N] fp32 -> Wt [N][K] bf16 (coalesced writes)
__global__ void tcast_k(const float* __restrict__ W, ushort_t* __restrict__ Wt, int K, int N) {
  int idx = blockIdx.x * blockDim.x + threadIdx.x;
  if (idx >= K * N) return;
  int n = idx / K, k = idx - n * K;
  Wt[idx] = f2bf(W[(size_t)k * N + n]);
}

// ---------------- bf16 MFMA GEMM: C[M,N] = A[M,K] @ Bt[N,K]^T ----------------
// 128x128 tile, 256 threads (4 waves in 2x2), BK=32, 16x16x32 MFMA, fp32 out.
#define LDA 40  // padded LDS row stride (bf16 elems)
__global__ __launch_bounds__(256) void mfma_gemm_k(const ushort_t* __restrict__ A,
                                                   const ushort_t* __restrict__ Bt,
                                                   float* __restrict__ C,
                                                   int M, int N, int K) {
  __shared__ ushort_t As[128 * LDA];
  __shared__ ushort_t Bs[128 * LDA];
  int tid = threadIdx.x;
  int lane = tid & 63;
  int wave = tid >> 6;
  int wm = (wave >> 1) * 64, wn = (wave & 1) * 64;
  int bm = blockIdx.y * 128, bn = blockIdx.x * 128;
  int lrow = lane & 15, lq = lane >> 4;

  f32x4 acc[4][4];
#pragma unroll
  for (int i = 0; i < 4; i++)
#pragma unroll
    for (int j = 0; j < 4; j++) acc[i][j] = 0.f;

  int srow = tid >> 2;          // 0..63
  int skc = (tid & 3) * 8;      // k elem offset within BK

  for (int k0 = 0; k0 < K; k0 += 32) {
    int gr0 = min(bm + srow, M - 1);
    int gr1 = min(bm + srow + 64, M - 1);
    short8 va0 = *(const short8*)&A[(size_t)gr0 * K + k0 + skc];
    short8 va1 = *(const short8*)&A[(size_t)gr1 * K + k0 + skc];
    short8 vb0 = *(const short8*)&Bt[(size_t)(bn + srow) * K + k0 + skc];
    short8 vb1 = *(const short8*)&Bt[(size_t)(bn + srow + 64) * K + k0 + skc];
    __syncthreads();
    *(short8*)&As[srow * LDA + skc] = va0;
    *(short8*)&As[(srow + 64) * LDA + skc] = va1;
    *(short8*)&Bs[srow * LDA + skc] = vb0;
    *(short8*)&Bs[(srow + 64) * LDA + skc] = vb1;
    __syncthreads();
    short8 af[4], bfr[4];
#pragma unroll
    for (int t = 0; t < 4; t++) {
      af[t]  = *(const short8*)&As[(wm + t * 16 + lrow) * LDA + lq * 8];
      bfr[t] = *(const short8*)&Bs[(wn + t * 16 + lrow) * LDA + lq * 8];
    }
#pragma unroll
    for (int i = 0; i < 4; i++)
#pragma unroll
      for (int j = 0; j < 4; j++)
        acc[i][j] = __builtin_amdgcn_mfma_f32_16x16x32_bf16(af[i], bfr[j], acc[i][j], 0, 0, 0);
  }

#pragma unroll
  for (int i = 0; i < 4; i++) {
    int row0 = bm + wm + i * 16 + lq * 4;  // C/D: col=lane&15, row=(lane>>4)*4+reg
#pragma unroll
    for (int j = 0; j < 4; j++) {
      int col = bn + wn + j * 16 + lrow;
#pragma unroll
      for (int r = 0; r < 4; r++) {
        int row = row0 + r;
        if (row < M) C[(size_t)row * N + col] = acc[i][j][r];
      }
    }
  }
}

// ---------------- alpha_src / alpha_dst: one wave per (n,h) ----------------
template <int C>
__global__ __launch_bounds__(256) void alpha_k(const float* __restrict__ h,
                                               const float* __restrict__ att_s,
                                               const float* __restrict__ att_d,
                                               float* __restrict__ osrc,
                                               float* __restrict__ odst, int NH) {
  int wid = (blockIdx.x * 256 + threadIdx.x) >> 6;
  int lane = threadIdx.x & 63;
  if (wid >= NH) return;
  int hh = wid & (HEADS - 1);
  const float* row = h + (size_t)wid * C;
  const float* ar = att_s + hh * C;
  const float* br = att_d + hh * C;
  float s = 0.f, d = 0.f;
#pragma unroll
  for (int c = lane; c < C; c += 64) {
    float v = row[c];
    s += v * ar[c];
    d += v * br[c];
  }
#pragma unroll
  for (int o = 32; o > 0; o >>= 1) {
    s += __shfl_down(s, o);
    d += __shfl_down(d, o);
  }
  if (lane == 0) { osrc[wid] = s; odst[wid] = d; }
}

// ---------------- edge logits -> exp, denom accumulation ----------------
__global__ void edge_k(const int* __restrict__ src, const int* __restrict__ dst,
                       const float* __restrict__ asrc, const float* __restrict__ adst,
                       float* __restrict__ ex, float* __restrict__ denom, int Etot) {
  int i = blockIdx.x * blockDim.x + threadIdx.x;
  if (i >= Etot * HEADS) return;
  int e = i >> 3, hh = i & 7;
  float v = asrc[src[e] * HEADS + hh] + adst[dst[e] * HEADS + hh];
  v = (v > 0.f) ? v : NEG * v;   // leaky_relu(0.2)
  float ev = expf(v);            // softmax is shift-invariant; |v| small -> no max needed
  ex[i] = ev;
  atomicAdd(&denom[dst[e] * HEADS + hh], ev);
}

// ---------------- CSR aggregation + bias + ELU ----------------
template <int CSHIFT, int REGS, typename OT>
__global__ __launch_bounds__(256) void aggregate_k(const float* __restrict__ h,
                                                   const float* __restrict__ ex,
                                                   const float* __restrict__ denom,
                                                   const int* __restrict__ offs,
                                                   const int* __restrict__ perm,
                                                   const int* __restrict__ src,
                                                   const float* __restrict__ bias,
                                                   OT* __restrict__ out) {
  const int F = 256 * REGS;
  int n = blockIdx.x;
  int t = threadIdx.x;
  float acc[REGS] = {};
  int hh[REGS];
#pragma unroll
  for (int j = 0; j < REGS; j++) hh[j] = (t + j * 256) >> CSHIFT;
  int e0 = offs[n], e1 = offs[n + 1];
  for (int i = e0; i < e1; i++) {
    int e = perm[i];
    int s = src[e];
    const float* row = h + (size_t)s * F;
#pragma unroll
    for (int j = 0; j < REGS; j++) acc[j] += ex[e * HEADS + hh[j]] * row[t + j * 256];
  }
#pragma unroll
  for (int j = 0; j < REGS; j++) {
    int c = t + j * 256;
    float v = acc[j] / denom[n * HEADS + hh[j]] + bias[c];
    v = (v > 0.f) ? v : expm1f(v);  // ELU
    if (sizeof(OT) == 2) ((ushort_t*)out)[(size_t)n * F + c] = f2bf(v);
    else ((float*)out)[(size_t)n * F + c] = v;
  }
}

// ---------------- batch boundaries (batch is sorted; no atomics) ----------------
__global__ void bounds_k(const int* __restrict__ batch, int* __restrict__ bstart,
                         int* __restrict__ bend, int Nn) {
  int i = blockIdx.x * blockDim.x + threadIdx.x;
  if (i >= Nn) return;
  int b = batch[i];
  if (i == 0 || batch[i - 1] != b) bstart[b] = i;
  if (i == Nn - 1 || batch[i + 1] != b) bend[b] = i + 1;
}

__global__ __launch_bounds__(256) void pool_k(const float* __restrict__ g,
                                              const int* __restrict__ batch,
                                              float* __restrict__ sums, int Nn) {
  int c = blockIdx.x * 256 + threadIdx.x;  // 0..511
  int n0 = blockIdx.y * 250;
  int n1 = min(n0 + 250, Nn);
  if (n0 >= n1) return;
  float acc = 0.f;
  int cur = batch[n0];
  for (int n = n0; n < n1; n++) {
    int b = batch[n];
    if (b != cur) { atomicAdd(&sums[cur * 512 + c], acc); acc = 0.f; cur = b; }
    acc += g[(size_t)n * 512 + c];
  }
  atomicAdd(&sums[cur * 512 + c], acc);
}

// ---------------- mean + fc1(elu) + fc2, one block ----------------
__global__ __launch_bounds__(512) void mlp_k(const float* __restrict__ sums,
                                             const int* __restrict__ bstart,
                                             const int* __restrict__ bend,
                                             const float* __restrict__ w1,
                                             const float* __restrict__ b1,
                                             const float* __restrict__ w2,
                                             const float* __restrict__ b2,
                                             float* __restrict__ out) {
  __shared__ float gm[16 * 512];
  __shared__ float t1[16 * 32];
  int t = threadIdx.x;
  for (int i = t; i < 16 * 512; i += 512) {
    int b = i >> 9;
    float c = (float)(bend[b] - bstart[b]);
    gm[i] = sums[i] / fmaxf(c, 1.f);
  }
  __syncthreads();
  {
    int b = t >> 5, j = t & 31;
    float s = b1[j];
    for (int k = 0; k < 512; k++) s += gm[(b << 9) + k] * w1[k * 32 + j];
    t1[t] = (s > 0.f) ? s : expm1f(s);
  }
  __syncthreads();
  if (t < 160) {
    int b = t / 10, j = t - b * 10;
    float s = b2[j];
#pragma unroll
    for (int k = 0; k < 32; k++) s += t1[b * 32 + k] * w2[k * 10 + j];
    out[t] = s;
  }
}

extern "C" void kernel_launch(void* const* d_in, const int* in_sizes, int n_in,
                              void* d_out, int out_size, void* d_ws, size_t ws_size,
                              hipStream_t stream) {
  const float* x   = (const float*)d_in[0];
  const int*   ei  = (const int*)d_in[1];
  const int* batch = (const int*)d_in[2];
  const float* W1  = (const float*)d_in[3];
  const float* as1 = (const float*)d_in[4];
  const float* ad1 = (const float*)d_in[5];
  const float* b1  = (const float*)d_in[6];
  const float* W2  = (const float*)d_in[7];
  const float* as2 = (const float*)d_in[8];
  const float* ad2 = (const float*)d_in[9];
  const float* b2  = (const float*)d_in[10];
  const float* f1w = (const float*)d_in[11];
  const float* f1b = (const float*)d_in[12];
  const float* f2w = (const float*)d_in[13];
  const float* f2b = (const float*)d_in[14];
  float* out = (float*)d_out;

  const int Nn = in_sizes[2];      // 10000
  const int E = in_sizes[1] / 2;   // 160000
  const int Etot = E + Nn;         // self loops appended

  // ---- workspace layout (4B words, 64-word aligned) ----
  size_t off = 0;
  auto alloc = [&](size_t elems) { size_t o = off; off += (elems + 63) & ~(size_t)63; return o; };
  int* wsi = (int*)d_ws;
  float* wsf = (float*)d_ws;

  size_t o_deg  = alloc(Nn);
  size_t o_den1 = alloc((size_t)Nn * 8);
  size_t o_den2 = alloc((size_t)Nn * 8);
  size_t o_pool = alloc(16 * 512);
  size_t o_bst  = alloc(64);
  size_t o_ben  = alloc(64);
  size_t zero_words = off;               // everything above is accumulated into -> zero each call
  size_t o_offs = alloc(Nn + 1);
  size_t o_cur  = alloc(Nn);
  size_t o_src  = alloc(Etot);
  size_t o_dst  = alloc(Etot);
  size_t o_perm = alloc(Etot);
  size_t o_asrc = alloc((size_t)Nn * 8);
  size_t o_adst = alloc((size_t)Nn * 8);
  size_t o_ex   = alloc((size_t)Etot * 8);
  size_t o_xb   = alloc((size_t)Nn * 128 / 2);   // x bf16  [N,128]
  size_t o_w1t  = alloc(1024 * 128 / 2);         // W1^T bf16 [1024,128]
  size_t o_w2t  = alloc(512 * 1024 / 2);         // W2^T bf16 [512,1024]
  size_t o_h    = alloc((size_t)Nn * 1024);      // h1 fp32, reused as h2
  size_t o_g    = alloc((size_t)Nn * 1024);      // g1 bf16 (first half), then g2 fp32

  ushort_t* xb  = (ushort_t*)(wsi + o_xb);
  ushort_t* w1t = (ushort_t*)(wsi + o_w1t);
  ushort_t* w2t = (ushort_t*)(wsi + o_w2t);
  ushort_t* g1b = (ushort_t*)(wsi + o_g);

  int eb = (Etot + 255) / 256;

  zero_k<<<512, 256, 0, stream>>>(wsi, (int)zero_words);
  prep_k<<<eb, 256, 0, stream>>>(ei, wsi + o_src, wsi + o_dst, E, Nn);
  count_k<<<eb, 256, 0, stream>>>(wsi + o_dst, wsi + o_deg, Etot);
  scan_k<<<1, 1024, 0, stream>>>(wsi + o_deg, wsi + o_offs, wsi + o_cur, Nn);
  scatter_k<<<eb, 256, 0, stream>>>(wsi + o_dst, wsi + o_cur, wsi + o_perm, Etot);

  // ---- casts for MFMA ----
  cast_k<<<(Nn * 128 / 4 + 255) / 256, 256, 0, stream>>>(x, xb, Nn * 128 / 4);
  tcast_k<<<(128 * 1024 + 255) / 256, 256, 0, stream>>>(W1, w1t, 128, 1024);
  tcast_k<<<(1024 * 512 + 255) / 256, 256, 0, stream>>>(W2, w2t, 1024, 512);

  // ---- layer 1: 128 -> 8x128 ----
  mfma_gemm_k<<<dim3(1024 / 128, (Nn + 127) / 128), 256, 0, stream>>>(xb, w1t, wsf + o_h, Nn, 1024, 128);
  alpha_k<128><<<(Nn * 8) / 4, 256, 0, stream>>>(wsf + o_h, as1, ad1, wsf + o_asrc, wsf + o_adst, Nn * 8);
  edge_k<<<(Etot * 8 + 255) / 256, 256, 0, stream>>>(wsi + o_src, wsi + o_dst, wsf + o_asrc,
                                                     wsf + o_adst, wsf + o_ex, wsf + o_den1, Etot);
  aggregate_k<7, 4, ushort_t><<<Nn, 256, 0, stream>>>(wsf + o_h, wsf + o_ex, wsf + o_den1, wsi + o_offs,
                                                      wsi + o_perm, wsi + o_src, b1, g1b);

  // ---- layer 2: 1024 -> 8x64 ----
  mfma_gemm_k<<<dim3(512 / 128, (Nn + 127) / 128), 256, 0, stream>>>(g1b, w2t, wsf + o_h, Nn, 512, 1024);
  alpha_k<64><<<(Nn * 8) / 4, 256, 0, stream>>>(wsf + o_h, as2, ad2, wsf + o_asrc, wsf + o_adst, Nn * 8);
  edge_k<<<(Etot * 8 + 255) / 256, 256, 0, stream>>>(wsi + o_src, wsi + o_dst, wsf + o_asrc,
                                                     wsf + o_adst, wsf + o_ex, wsf + o_den2, Etot);
  aggregate_k<6, 2, float><<<Nn, 256, 0, stream>>>(wsf + o_h, wsf + o_ex, wsf + o_den2, wsi + o_offs,
                                                   wsi + o_perm, wsi + o_src, b2, wsf + o_g);

  // ---- pool + MLP ----
  bounds_k<<<(Nn + 255) / 256, 256, 0, stream>>>(batch, wsi + o_bst, wsi + o_ben, Nn);
  pool_k<<<dim3(2, (Nn + 249) / 250), 256, 0, stream>>>(wsf + o_g, batch, wsf + o_pool, Nn);
  mlp_k<<<1, 512, 0, stream>>>(wsf + o_pool, wsi + o_bst, wsi + o_ben, f1w, f1b, f2w, f2b, out);
}

// Round 4
// 392.301 us; speedup vs baseline: 1.9360x; 1.2299x over previous
//
#include <hip/hip_runtime.h>
#include <math.h>

#define HEADS 8
#define NEG 0.2f

typedef unsigned short ushort_t;
typedef __attribute__((ext_vector_type(8))) short short8;
typedef float f32x4 __attribute__((ext_vector_type(4)));

__device__ inline ushort_t f2bf(float f) {
  union { float f; unsigned u; } v; v.f = f;
  unsigned r = (v.u + 0x7FFF + ((v.u >> 16) & 1)) >> 16;  // RNE
  return (ushort_t)r;
}

// ---------------- utility: zero a word region ----------------
__global__ void zero_k(int* __restrict__ p, int n) {
  int i = blockIdx.x * blockDim.x + threadIdx.x;
  int stride = gridDim.x * blockDim.x;
  for (; i < n; i += stride) p[i] = 0;
}

// ---------------- edge prep: append self loops ----------------
__global__ void prep_k(const int* __restrict__ ei, int* __restrict__ src,
                       int* __restrict__ dst, int E, int Nn) {
  int i = blockIdx.x * blockDim.x + threadIdx.x;
  int tot = E + Nn;
  if (i >= tot) return;
  if (i < E) { src[i] = ei[i]; dst[i] = ei[E + i]; }
  else       { src[i] = i - E; dst[i] = i - E; }
}

__global__ void count_k(const int* __restrict__ dst, int* __restrict__ deg, int Etot) {
  int i = blockIdx.x * blockDim.x + threadIdx.x;
  if (i < Etot) atomicAdd(&deg[dst[i]], 1);
}

// single-block scan over N, wave-shuffle based (2 barriers per 1024-chunk)
__global__ __launch_bounds__(1024) void scan_k(const int* __restrict__ deg,
                                               int* __restrict__ offs,
                                               int* __restrict__ cursor, int Nn) {
  __shared__ int wtot[16];
  __shared__ int wexcl[16];
  __shared__ int soff_s;
  int t = threadIdx.x;
  int lane = t & 63, w = t >> 6;
  if (t == 0) soff_s = 0;
  __syncthreads();
  for (int base = 0; base < Nn; base += 1024) {
    int v = (base + t < Nn) ? deg[base + t] : 0;
    int sc = v;
#pragma unroll
    for (int o = 1; o < 64; o <<= 1) {
      int x = __shfl_up(sc, o);
      if (lane >= o) sc += x;
    }
    if (lane == 63) wtot[w] = sc;
    __syncthreads();
    if (w == 0) {
      int tv = (lane < 16) ? wtot[lane] : 0;
      int ts = tv;
#pragma unroll
      for (int o = 1; o < 16; o <<= 1) {
        int x = __shfl_up(ts, o);
        if (lane >= o) ts += x;
      }
      if (lane < 16) wexcl[lane] = ts - tv;
      if (lane == 15) wtot[15] = ts;  // chunk total
    }
    __syncthreads();
    int soff = soff_s;
    int excl = soff + wexcl[w] + sc - v;
    if (base + t < Nn) { offs[base + t] = excl; cursor[base + t] = excl; }
    int chunk_total = wtot[15];
    __syncthreads();
    if (t == 0) soff_s = soff + chunk_total;
    __syncthreads();
  }
  if (t == 0) offs[Nn] = soff_s;
}

__global__ void scatter_k(const int* __restrict__ dst, int* __restrict__ cursor,
                          int* __restrict__ perm, int Etot) {
  int i = blockIdx.x * blockDim.x + threadIdx.x;
  if (i < Etot) { int p = atomicAdd(&cursor[dst[i]], 1); perm[p] = i; }
}

// ---------------- casts ----------------
__global__ void cast_k(const float* __restrict__ in, ushort_t* __restrict__ out, int n4) {
  int i = blockIdx.x * blockDim.x + threadIdx.x;
  if (i >= n4) return;
  float4 v = ((const float4*)in)[i];
  ushort_t o[4] = {f2bf(v.x), f2bf(v.y), f2bf(v.z), f2bf(v.w)};
  *(uint2*)&out[i * 4] = *(uint2*)o;
}

// W [K][N] fp32 -> Wt [N][K] bf16 (coalesced writes)
__global__ void tcast_k(const float* __restrict__ W, ushort_t* __restrict__ Wt, int K, int N) {
  int idx = blockIdx.x * blockDim.x + threadIdx.x;
  if (idx >= K * N) return;
  int n = idx / K, k = idx - n * K;
  Wt[idx] = f2bf(W[(size_t)k * N + n]);
}

// ------- bf16 MFMA GEMM + fused alpha epilogue: Cb[M,N](bf16) = A @ Bt^T -------
// 128x128 tile, 256 threads (4 waves 2x2), BK=32, 16x16x32 MFMA.
// Epilogue: per-row dot with att_s/att_d over this wave's 64 cols (one head's
// chunk: layer1 128ch/head -> half-head per wave, layer2 64ch/head -> one head),
// 4x shfl_xor reduce, atomicAdd into asrc/adst (zeroed per call).
#define LDA 40  // padded LDS row stride (bf16 elems)
__global__ __launch_bounds__(256) void mfma_gemm_k(const ushort_t* __restrict__ A,
                                                   const ushort_t* __restrict__ Bt,
                                                   ushort_t* __restrict__ Cb,
                                                   const float* __restrict__ att_s,
                                                   const float* __restrict__ att_d,
                                                   float* __restrict__ asrc,
                                                   float* __restrict__ adst,
                                                   int M, int N, int K, int CSHIFT) {
  __shared__ ushort_t As[128 * LDA];
  __shared__ ushort_t Bs[128 * LDA];
  int tid = threadIdx.x;
  int lane = tid & 63;
  int wave = tid >> 6;
  int wm = (wave >> 1) * 64, wn = (wave & 1) * 64;
  int bm = blockIdx.y * 128, bn = blockIdx.x * 128;
  int lrow = lane & 15, lq = lane >> 4;

  f32x4 acc[4][4];
#pragma unroll
  for (int i = 0; i < 4; i++)
#pragma unroll
    for (int j = 0; j < 4; j++) acc[i][j] = 0.f;

  int srow = tid >> 2;          // 0..63
  int skc = (tid & 3) * 8;      // k elem offset within BK

  for (int k0 = 0; k0 < K; k0 += 32) {
    int gr0 = min(bm + srow, M - 1);
    int gr1 = min(bm + srow + 64, M - 1);
    short8 va0 = *(const short8*)&A[(size_t)gr0 * K + k0 + skc];
    short8 va1 = *(const short8*)&A[(size_t)gr1 * K + k0 + skc];
    short8 vb0 = *(const short8*)&Bt[(size_t)(bn + srow) * K + k0 + skc];
    short8 vb1 = *(const short8*)&Bt[(size_t)(bn + srow + 64) * K + k0 + skc];
    __syncthreads();
    *(short8*)&As[srow * LDA + skc] = va0;
    *(short8*)&As[(srow + 64) * LDA + skc] = va1;
    *(short8*)&Bs[srow * LDA + skc] = vb0;
    *(short8*)&Bs[(srow + 64) * LDA + skc] = vb1;
    __syncthreads();
    short8 af[4], bfr[4];
#pragma unroll
    for (int t = 0; t < 4; t++) {
      af[t]  = *(const short8*)&As[(wm + t * 16 + lrow) * LDA + lq * 8];
      bfr[t] = *(const short8*)&Bs[(wn + t * 16 + lrow) * LDA + lq * 8];
    }
#pragma unroll
    for (int i = 0; i < 4; i++)
#pragma unroll
      for (int j = 0; j < 4; j++)
        acc[i][j] = __builtin_amdgcn_mfma_f32_16x16x32_bf16(af[i], bfr[j], acc[i][j], 0, 0, 0);
  }

  // ---- fused alpha partials (fp32, pre-rounding) ----
  {
    int hh = (bn + wn) >> CSHIFT;
    float avs[4], avd[4];
#pragma unroll
    for (int j = 0; j < 4; j++) {
      int col = bn + wn + j * 16 + lrow;  // att [H][N/H] flat == column index
      avs[j] = att_s[col];
      avd[j] = att_d[col];
    }
#pragma unroll
    for (int i = 0; i < 4; i++) {
#pragma unroll
      for (int r = 0; r < 4; r++) {
        float ps = 0.f, pd = 0.f;
#pragma unroll
        for (int j = 0; j < 4; j++) {
          float v = acc[i][j][r];
          ps += v * avs[j];
          pd += v * avd[j];
        }
#pragma unroll
        for (int o = 1; o < 16; o <<= 1) {
          ps += __shfl_xor(ps, o);
          pd += __shfl_xor(pd, o);
        }
        int row = bm + wm + i * 16 + lq * 4 + r;
        if (lrow == 0 && row < M) {
          atomicAdd(&asrc[row * HEADS + hh], ps);
          atomicAdd(&adst[row * HEADS + hh], pd);
        }
      }
    }
  }

  // ---- bf16 store ----
#pragma unroll
  for (int i = 0; i < 4; i++) {
    int row0 = bm + wm + i * 16 + lq * 4;  // C/D: col=lane&15, row=(lane>>4)*4+reg
#pragma unroll
    for (int j = 0; j < 4; j++) {
      int col = bn + wn + j * 16 + lrow;
#pragma unroll
      for (int r = 0; r < 4; r++) {
        int row = row0 + r;
        if (row < M) Cb[(size_t)row * N + col] = f2bf(acc[i][j][r]);
      }
    }
  }
}

// ---------------- edge logits -> exp, denom accumulation ----------------
__global__ void edge_k(const int* __restrict__ src, const int* __restrict__ dst,
                       const float* __restrict__ asrc, const float* __restrict__ adst,
                       float* __restrict__ ex, float* __restrict__ denom, int Etot) {
  int i = blockIdx.x * blockDim.x + threadIdx.x;
  if (i >= Etot * HEADS) return;
  int e = i >> 3, hh = i & 7;
  float v = asrc[src[e] * HEADS + hh] + adst[dst[e] * HEADS + hh];
  v = (v > 0.f) ? v : NEG * v;   // leaky_relu(0.2)
  float ev = expf(v);            // softmax is shift-invariant; |v| small -> no max needed
  ex[i] = ev;
  atomicAdd(&denom[dst[e] * HEADS + hh], ev);
}

// ---------------- CSR aggregation (bf16 gather) + bias + ELU ----------------
// block per node; thread t owns channel pairs c0 = 2t + j*512; F = 512*PAIRS.
template <int CSHIFT, int PAIRS, typename OT>
__global__ __launch_bounds__(256) void aggregate_k(const ushort_t* __restrict__ hb,
                                                   const float* __restrict__ ex,
                                                   const float* __restrict__ denom,
                                                   const int* __restrict__ offs,
                                                   const int* __restrict__ perm,
                                                   const int* __restrict__ src,
                                                   const float* __restrict__ bias,
                                                   OT* __restrict__ out) {
  const int F = 512 * PAIRS;
  int n = blockIdx.x;
  int t = threadIdx.x;
  float2 acc[PAIRS];
  int hh[PAIRS], c0[PAIRS];
#pragma unroll
  for (int j = 0; j < PAIRS; j++) {
    acc[j] = make_float2(0.f, 0.f);
    c0[j] = 2 * t + j * 512;       // pair (c0, c0+1) always within one head
    hh[j] = c0[j] >> CSHIFT;
  }
  int e0 = offs[n], e1 = offs[n + 1];
  for (int i = e0; i < e1; i++) {
    int e = perm[i];
    int s = src[e];
    const ushort_t* row = hb + (size_t)s * F;
#pragma unroll
    for (int j = 0; j < PAIRS; j++) {
      float w = ex[e * HEADS + hh[j]];
      unsigned v = *(const unsigned*)&row[c0[j]];
      union { unsigned u; float f; } lo, hi;
      lo.u = v << 16; hi.u = v & 0xffff0000u;
      acc[j].x += w * lo.f;
      acc[j].y += w * hi.f;
    }
  }
#pragma unroll
  for (int j = 0; j < PAIRS; j++) {
    float dn = denom[n * HEADS + hh[j]];
    float v0 = acc[j].x / dn + bias[c0[j]];
    float v1 = acc[j].y / dn + bias[c0[j] + 1];
    v0 = (v0 > 0.f) ? v0 : expm1f(v0);  // ELU
    v1 = (v1 > 0.f) ? v1 : expm1f(v1);
    if (sizeof(OT) == 2) {
      unsigned pv = (unsigned)f2bf(v0) | ((unsigned)f2bf(v1) << 16);
      *(unsigned*)&((ushort_t*)out)[(size_t)n * F + c0[j]] = pv;
    } else {
      *(float2*)&((float*)out)[(size_t)n * F + c0[j]] = make_float2(v0, v1);
    }
  }
}

// ---------------- batch boundaries (batch is sorted; no atomics) ----------------
__global__ void bounds_k(const int* __restrict__ batch, int* __restrict__ bstart,
                         int* __restrict__ bend, int Nn) {
  int i = blockIdx.x * blockDim.x + threadIdx.x;
  if (i >= Nn) return;
  int b = batch[i];
  if (i == 0 || batch[i - 1] != b) bstart[b] = i;
  if (i == Nn - 1 || batch[i + 1] != b) bend[b] = i + 1;
}

__global__ __launch_bounds__(256) void pool_k(const float* __restrict__ g,
                                              const int* __restrict__ batch,
                                              float* __restrict__ sums, int Nn) {
  int c = blockIdx.x * 256 + threadIdx.x;  // 0..511
  int n0 = blockIdx.y * 50;
  int n1 = min(n0 + 50, Nn);
  if (n0 >= n1) return;
  float acc = 0.f;
  int cur = batch[n0];
  for (int n = n0; n < n1; n++) {
    int b = batch[n];
    if (b != cur) { atomicAdd(&sums[cur * 512 + c], acc); acc = 0.f; cur = b; }
    acc += g[(size_t)n * 512 + c];
  }
  atomicAdd(&sums[cur * 512 + c], acc);
}

// ---------------- mean + fc1(elu) + fc2, one block ----------------
__global__ __launch_bounds__(512) void mlp_k(const float* __restrict__ sums,
                                             const int* __restrict__ bstart,
                                             const int* __restrict__ bend,
                                             const float* __restrict__ w1,
                                             const float* __restrict__ b1,
                                             const float* __restrict__ w2,
                                             const float* __restrict__ b2,
                                             float* __restrict__ out) {
  __shared__ float gm[16 * 512];
  __shared__ float t1[16 * 32];
  int t = threadIdx.x;
  for (int i = t; i < 16 * 512; i += 512) {
    int b = i >> 9;
    float c = (float)(bend[b] - bstart[b]);
    gm[i] = sums[i] / fmaxf(c, 1.f);
  }
  __syncthreads();
  {
    int b = t >> 5, j = t & 31;
    float s = b1[j];
    for (int k = 0; k < 512; k++) s += gm[(b << 9) + k] * w1[k * 32 + j];
    t1[t] = (s > 0.f) ? s : expm1f(s);
  }
  __syncthreads();
  if (t < 160) {
    int b = t / 10, j = t - b * 10;
    float s = b2[j];
#pragma unroll
    for (int k = 0; k < 32; k++) s += t1[b * 32 + k] * w2[k * 10 + j];
    out[t] = s;
  }
}

extern "C" void kernel_launch(void* const* d_in, const int* in_sizes, int n_in,
                              void* d_out, int out_size, void* d_ws, size_t ws_size,
                              hipStream_t stream) {
  const float* x   = (const float*)d_in[0];
  const int*   ei  = (const int*)d_in[1];
  const int* batch = (const int*)d_in[2];
  const float* W1  = (const float*)d_in[3];
  const float* as1 = (const float*)d_in[4];
  const float* ad1 = (const float*)d_in[5];
  const float* b1  = (const float*)d_in[6];
  const float* W2  = (const float*)d_in[7];
  const float* as2 = (const float*)d_in[8];
  const float* ad2 = (const float*)d_in[9];
  const float* b2  = (const float*)d_in[10];
  const float* f1w = (const float*)d_in[11];
  const float* f1b = (const float*)d_in[12];
  const float* f2w = (const float*)d_in[13];
  const float* f2b = (const float*)d_in[14];
  float* out = (float*)d_out;

  const int Nn = in_sizes[2];      // 10000
  const int E = in_sizes[1] / 2;   // 160000
  const int Etot = E + Nn;         // self loops appended

  // ---- workspace layout (4B words, 64-word aligned) ----
  size_t off = 0;
  auto alloc = [&](size_t elems) { size_t o = off; off += (elems + 63) & ~(size_t)63; return o; };
  int* wsi = (int*)d_ws;
  float* wsf = (float*)d_ws;

  size_t o_deg  = alloc(Nn);
  size_t o_den1 = alloc((size_t)Nn * 8);
  size_t o_den2 = alloc((size_t)Nn * 8);
  size_t o_pool = alloc(16 * 512);
  size_t o_bst  = alloc(64);
  size_t o_ben  = alloc(64);
  size_t o_as1  = alloc((size_t)Nn * 8);
  size_t o_ad1  = alloc((size_t)Nn * 8);
  size_t o_as2  = alloc((size_t)Nn * 8);
  size_t o_ad2  = alloc((size_t)Nn * 8);
  size_t zero_words = off;               // accumulated-into buffers -> zero each call
  size_t o_offs = alloc(Nn + 1);
  size_t o_cur  = alloc(Nn);
  size_t o_src  = alloc(Etot);
  size_t o_dst  = alloc(Etot);
  size_t o_perm = alloc(Etot);
  size_t o_ex   = alloc((size_t)Etot * 8);
  size_t o_xb   = alloc((size_t)Nn * 128 / 2);   // x bf16  [N,128]
  size_t o_w1t  = alloc(1024 * 128 / 2);         // W1^T bf16 [1024,128]
  size_t o_w2t  = alloc(512 * 1024 / 2);         // W2^T bf16 [512,1024]
  size_t o_h    = alloc((size_t)Nn * 1024 / 2);  // h bf16 [N,1024] (layer2 uses first half)
  size_t o_g    = alloc((size_t)Nn * 1024);      // g1 bf16 (first half) then g2 fp32 (overwrites)

  ushort_t* xb  = (ushort_t*)(wsi + o_xb);
  ushort_t* w1t = (ushort_t*)(wsi + o_w1t);
  ushort_t* w2t = (ushort_t*)(wsi + o_w2t);
  ushort_t* hb  = (ushort_t*)(wsi + o_h);
  ushort_t* g1b = (ushort_t*)(wsi + o_g);

  int eb = (Etot + 255) / 256;

  zero_k<<<512, 256, 0, stream>>>(wsi, (int)zero_words);
  prep_k<<<eb, 256, 0, stream>>>(ei, wsi + o_src, wsi + o_dst, E, Nn);
  count_k<<<eb, 256, 0, stream>>>(wsi + o_dst, wsi + o_deg, Etot);
  scan_k<<<1, 1024, 0, stream>>>(wsi + o_deg, wsi + o_offs, wsi + o_cur, Nn);
  scatter_k<<<eb, 256, 0, stream>>>(wsi + o_dst, wsi + o_cur, wsi + o_perm, Etot);

  // ---- casts for MFMA ----
  cast_k<<<(Nn * 128 / 4 + 255) / 256, 256, 0, stream>>>(x, xb, Nn * 128 / 4);
  tcast_k<<<(128 * 1024 + 255) / 256, 256, 0, stream>>>(W1, w1t, 128, 1024);
  tcast_k<<<(1024 * 512 + 255) / 256, 256, 0, stream>>>(W2, w2t, 1024, 512);

  // ---- layer 1: 128 -> 8x128 ----
  mfma_gemm_k<<<dim3(1024 / 128, (Nn + 127) / 128), 256, 0, stream>>>(
      xb, w1t, hb, as1, ad1, wsf + o_as1, wsf + o_ad1, Nn, 1024, 128, 7);
  edge_k<<<(Etot * 8 + 255) / 256, 256, 0, stream>>>(wsi + o_src, wsi + o_dst, wsf + o_as1,
                                                     wsf + o_ad1, wsf + o_ex, wsf + o_den1, Etot);
  aggregate_k<7, 2, ushort_t><<<Nn, 256, 0, stream>>>(hb, wsf + o_ex, wsf + o_den1, wsi + o_offs,
                                                      wsi + o_perm, wsi + o_src, b1, g1b);

  // ---- layer 2: 1024 -> 8x64 ----
  mfma_gemm_k<<<dim3(512 / 128, (Nn + 127) / 128), 256, 0, stream>>>(
      g1b, w2t, hb, as2, ad2, wsf + o_as2, wsf + o_ad2, Nn, 512, 1024, 6);
  edge_k<<<(Etot * 8 + 255) / 256, 256, 0, stream>>>(wsi + o_src, wsi + o_dst, wsf + o_as2,
                                                     wsf + o_ad2, wsf + o_ex, wsf + o_den2, Etot);
  aggregate_k<6, 1, float><<<Nn, 256, 0, stream>>>(hb, wsf + o_ex, wsf + o_den2, wsi + o_offs,
                                                   wsi + o_perm, wsi + o_src, b2, wsf + o_g);

  // ---- pool + MLP ----
  bounds_k<<<(Nn + 255) / 256, 256, 0, stream>>>(batch, wsi + o_bst, wsi + o_ben, Nn);
  pool_k<<<dim3(2, (Nn + 49) / 50), 256, 0, stream>>>(wsf + o_g, batch, wsf + o_pool, Nn);
  mlp_k<<<1, 512, 0, stream>>>(wsf + o_pool, wsi + o_bst, wsi + o_ben, f1w, f1b, f2w, f2b, out);
}

// Round 5
// 331.042 us; speedup vs baseline: 2.2943x; 1.1850x over previous
//
#include <hip/hip_runtime.h>
#include <math.h>

#define HEADS 8
#define NEG 0.2f

typedef unsigned short ushort_t;
typedef __attribute__((ext_vector_type(8))) short short8;
typedef float f32x4 __attribute__((ext_vector_type(4)));

__device__ inline ushort_t f2bf(float f) {
  union { float f; unsigned u; } v; v.f = f;
  unsigned r = (v.u + 0x7FFF + ((v.u >> 16) & 1)) >> 16;  // RNE
  return (ushort_t)r;
}

__device__ inline float4 bf4(uint2 v) {
  union { unsigned u; float f; } a, b, c, d;
  a.u = v.x << 16; b.u = v.x & 0xffff0000u;
  c.u = v.y << 16; d.u = v.y & 0xffff0000u;
  return make_float4(a.f, b.f, c.f, d.f);
}

// ---------------- utility: zero a word region ----------------
__global__ void zero_k(int* __restrict__ p, int n) {
  int i = blockIdx.x * blockDim.x + threadIdx.x;
  int stride = gridDim.x * blockDim.x;
  for (; i < n; i += stride) p[i] = 0;
}

// ---------------- edge prep: append self loops ----------------
__global__ void prep_k(const int* __restrict__ ei, int* __restrict__ src,
                       int* __restrict__ dst, int E, int Nn) {
  int i = blockIdx.x * blockDim.x + threadIdx.x;
  int tot = E + Nn;
  if (i >= tot) return;
  if (i < E) { src[i] = ei[i]; dst[i] = ei[E + i]; }
  else       { src[i] = i - E; dst[i] = i - E; }
}

__global__ void count_k(const int* __restrict__ dst, int* __restrict__ deg, int Etot) {
  int i = blockIdx.x * blockDim.x + threadIdx.x;
  if (i < Etot) atomicAdd(&deg[dst[i]], 1);
}

// single-block scan over N, wave-shuffle based (2 barriers per 1024-chunk)
__global__ __launch_bounds__(1024) void scan_k(const int* __restrict__ deg,
                                               int* __restrict__ offs,
                                               int* __restrict__ cursor, int Nn) {
  __shared__ int wtot[16];
  __shared__ int wexcl[16];
  __shared__ int soff_s;
  int t = threadIdx.x;
  int lane = t & 63, w = t >> 6;
  if (t == 0) soff_s = 0;
  __syncthreads();
  for (int base = 0; base < Nn; base += 1024) {
    int v = (base + t < Nn) ? deg[base + t] : 0;
    int sc = v;
#pragma unroll
    for (int o = 1; o < 64; o <<= 1) {
      int x = __shfl_up(sc, o);
      if (lane >= o) sc += x;
    }
    if (lane == 63) wtot[w] = sc;
    __syncthreads();
    if (w == 0) {
      int tv = (lane < 16) ? wtot[lane] : 0;
      int ts = tv;
#pragma unroll
      for (int o = 1; o < 16; o <<= 1) {
        int x = __shfl_up(ts, o);
        if (lane >= o) ts += x;
      }
      if (lane < 16) wexcl[lane] = ts - tv;
      if (lane == 15) wtot[15] = ts;  // chunk total
    }
    __syncthreads();
    int soff = soff_s;
    int excl = soff + wexcl[w] + sc - v;
    if (base + t < Nn) { offs[base + t] = excl; cursor[base + t] = excl; }
    int chunk_total = wtot[15];
    __syncthreads();
    if (t == 0) soff_s = soff + chunk_total;
    __syncthreads();
  }
  if (t == 0) offs[Nn] = soff_s;
}

// scatter src/dst values directly into CSR slot order (no perm indirection)
__global__ void scatter_k(const int* __restrict__ src, const int* __restrict__ dst,
                          int* __restrict__ cursor, int* __restrict__ psrc,
                          int* __restrict__ pdst, int Etot) {
  int i = blockIdx.x * blockDim.x + threadIdx.x;
  if (i >= Etot) return;
  int d = dst[i];
  int p = atomicAdd(&cursor[d], 1);
  psrc[p] = src[i];
  pdst[p] = d;
}

// ---------------- casts ----------------
__global__ void cast_k(const float* __restrict__ in, ushort_t* __restrict__ out, int n4) {
  int i = blockIdx.x * blockDim.x + threadIdx.x;
  if (i >= n4) return;
  float4 v = ((const float4*)in)[i];
  ushort_t o[4] = {f2bf(v.x), f2bf(v.y), f2bf(v.z), f2bf(v.w)};
  *(uint2*)&out[i * 4] = *(uint2*)o;
}

// W [K][N] fp32 -> Wt [N][K] bf16 (coalesced writes)
__global__ void tcast_k(const float* __restrict__ W, ushort_t* __restrict__ Wt, int K, int N) {
  int idx = blockIdx.x * blockDim.x + threadIdx.x;
  if (idx >= K * N) return;
  int n = idx / K, k = idx - n * K;
  Wt[idx] = f2bf(W[(size_t)k * N + n]);
}

// ------- bf16 MFMA GEMM + fused alpha epilogue: Cb[M,N](bf16) = A @ Bt^T -------
// 128x128 tile, 256 threads (4 waves 2x2), BK=32, 16x16x32 MFMA.
#define LDA 40  // padded LDS row stride (bf16 elems)
__global__ __launch_bounds__(256) void mfma_gemm_k(const ushort_t* __restrict__ A,
                                                   const ushort_t* __restrict__ Bt,
                                                   ushort_t* __restrict__ Cb,
                                                   const float* __restrict__ att_s,
                                                   const float* __restrict__ att_d,
                                                   float* __restrict__ asrc,
                                                   float* __restrict__ adst,
                                                   int M, int N, int K, int CSHIFT) {
  __shared__ ushort_t As[128 * LDA];
  __shared__ ushort_t Bs[128 * LDA];
  int tid = threadIdx.x;
  int lane = tid & 63;
  int wave = tid >> 6;
  int wm = (wave >> 1) * 64, wn = (wave & 1) * 64;
  int bm = blockIdx.y * 128, bn = blockIdx.x * 128;
  int lrow = lane & 15, lq = lane >> 4;

  f32x4 acc[4][4];
#pragma unroll
  for (int i = 0; i < 4; i++)
#pragma unroll
    for (int j = 0; j < 4; j++) acc[i][j] = 0.f;

  int srow = tid >> 2;          // 0..63
  int skc = (tid & 3) * 8;      // k elem offset within BK

  for (int k0 = 0; k0 < K; k0 += 32) {
    int gr0 = min(bm + srow, M - 1);
    int gr1 = min(bm + srow + 64, M - 1);
    short8 va0 = *(const short8*)&A[(size_t)gr0 * K + k0 + skc];
    short8 va1 = *(const short8*)&A[(size_t)gr1 * K + k0 + skc];
    short8 vb0 = *(const short8*)&Bt[(size_t)(bn + srow) * K + k0 + skc];
    short8 vb1 = *(const short8*)&Bt[(size_t)(bn + srow + 64) * K + k0 + skc];
    __syncthreads();
    *(short8*)&As[srow * LDA + skc] = va0;
    *(short8*)&As[(srow + 64) * LDA + skc] = va1;
    *(short8*)&Bs[srow * LDA + skc] = vb0;
    *(short8*)&Bs[(srow + 64) * LDA + skc] = vb1;
    __syncthreads();
    short8 af[4], bfr[4];
#pragma unroll
    for (int t = 0; t < 4; t++) {
      af[t]  = *(const short8*)&As[(wm + t * 16 + lrow) * LDA + lq * 8];
      bfr[t] = *(const short8*)&Bs[(wn + t * 16 + lrow) * LDA + lq * 8];
    }
#pragma unroll
    for (int i = 0; i < 4; i++)
#pragma unroll
      for (int j = 0; j < 4; j++)
        acc[i][j] = __builtin_amdgcn_mfma_f32_16x16x32_bf16(af[i], bfr[j], acc[i][j], 0, 0, 0);
  }

  // ---- fused alpha partials (fp32, pre-rounding) ----
  {
    int hh = (bn + wn) >> CSHIFT;
    float avs[4], avd[4];
#pragma unroll
    for (int j = 0; j < 4; j++) {
      int col = bn + wn + j * 16 + lrow;  // att [H][N/H] flat == column index
      avs[j] = att_s[col];
      avd[j] = att_d[col];
    }
#pragma unroll
    for (int i = 0; i < 4; i++) {
#pragma unroll
      for (int r = 0; r < 4; r++) {
        float ps = 0.f, pd = 0.f;
#pragma unroll
        for (int j = 0; j < 4; j++) {
          float v = acc[i][j][r];
          ps += v * avs[j];
          pd += v * avd[j];
        }
#pragma unroll
        for (int o = 1; o < 16; o <<= 1) {
          ps += __shfl_xor(ps, o);
          pd += __shfl_xor(pd, o);
        }
        int row = bm + wm + i * 16 + lq * 4 + r;
        if (lrow == 0 && row < M) {
          atomicAdd(&asrc[row * HEADS + hh], ps);
          atomicAdd(&adst[row * HEADS + hh], pd);
        }
      }
    }
  }

  // ---- bf16 store ----
#pragma unroll
  for (int i = 0; i < 4; i++) {
    int row0 = bm + wm + i * 16 + lq * 4;  // C/D: col=lane&15, row=(lane>>4)*4+reg
#pragma unroll
    for (int j = 0; j < 4; j++) {
      int col = bn + wn + j * 16 + lrow;
#pragma unroll
      for (int r = 0; r < 4; r++) {
        int row = row0 + r;
        if (row < M) Cb[(size_t)row * N + col] = f2bf(acc[i][j][r]);
      }
    }
  }
}

// -------- edge logits -> exp, slot order, no atomics (denom fused into agg) -----
__global__ void edge_k(const int* __restrict__ psrc, const int* __restrict__ pdst,
                       const float* __restrict__ asrc, const float* __restrict__ adst,
                       float* __restrict__ exv, int Etot) {
  int i = blockIdx.x * blockDim.x + threadIdx.x;
  if (i >= Etot * HEADS) return;
  int sl = i >> 3, hh = i & 7;
  float v = asrc[psrc[sl] * HEADS + hh] + adst[pdst[sl] * HEADS + hh];
  v = (v > 0.f) ? v : NEG * v;   // leaky_relu(0.2)
  exv[i] = expf(v);              // shift-invariant softmax; |v| small
}

// ---------------- CSR aggregation (bf16 gather) + softmax denom + bias + ELU ----
// TPN threads per node (=F/4); thread owns 4 consecutive channels (uint2 load).
// Unroll-2 over edges: two independent gathers in flight.
template <int F, int CSHIFT, int TPN, typename OT>
__global__ __launch_bounds__(256) void aggregate_k(const ushort_t* __restrict__ hb,
                                                   const float* __restrict__ exv,
                                                   const int* __restrict__ offs,
                                                   const int* __restrict__ psrc,
                                                   const float* __restrict__ bias,
                                                   OT* __restrict__ out, int Nn) {
  int t = threadIdx.x;
  int n = blockIdx.x * (256 / TPN) + t / TPN;
  if (n >= Nn) return;
  int tt = t % TPN;
  int c0 = 4 * tt;
  int hh = c0 >> CSHIFT;
  float4 acc = make_float4(0.f, 0.f, 0.f, 0.f);
  float wsum = 0.f;
  int e0 = offs[n], e1 = offs[n + 1];
  int i = e0;
  for (; i + 2 <= e1; i += 2) {
    int s0 = psrc[i], s1 = psrc[i + 1];
    float w0 = exv[(size_t)i * 8 + hh];
    float w1 = exv[(size_t)(i + 1) * 8 + hh];
    uint2 r0 = *(const uint2*)&hb[(size_t)s0 * F + c0];
    uint2 r1 = *(const uint2*)&hb[(size_t)s1 * F + c0];
    float4 f0 = bf4(r0), f1 = bf4(r1);
    wsum += w0 + w1;
    acc.x += w0 * f0.x + w1 * f1.x;
    acc.y += w0 * f0.y + w1 * f1.y;
    acc.z += w0 * f0.z + w1 * f1.z;
    acc.w += w0 * f0.w + w1 * f1.w;
  }
  if (i < e1) {
    int s0 = psrc[i];
    float w0 = exv[(size_t)i * 8 + hh];
    float4 f0 = bf4(*(const uint2*)&hb[(size_t)s0 * F + c0]);
    wsum += w0;
    acc.x += w0 * f0.x; acc.y += w0 * f0.y;
    acc.z += w0 * f0.z; acc.w += w0 * f0.w;
  }
  float inv = 1.f / wsum;
  float v0 = acc.x * inv + bias[c0];
  float v1 = acc.y * inv + bias[c0 + 1];
  float v2 = acc.z * inv + bias[c0 + 2];
  float v3 = acc.w * inv + bias[c0 + 3];
  v0 = (v0 > 0.f) ? v0 : expm1f(v0);
  v1 = (v1 > 0.f) ? v1 : expm1f(v1);
  v2 = (v2 > 0.f) ? v2 : expm1f(v2);
  v3 = (v3 > 0.f) ? v3 : expm1f(v3);
  if (sizeof(OT) == 2) {
    unsigned p0 = (unsigned)f2bf(v0) | ((unsigned)f2bf(v1) << 16);
    unsigned p1 = (unsigned)f2bf(v2) | ((unsigned)f2bf(v3) << 16);
    *(uint2*)&((ushort_t*)out)[(size_t)n * F + c0] = make_uint2(p0, p1);
  } else {
    *(float4*)&((float*)out)[(size_t)n * F + c0] = make_float4(v0, v1, v2, v3);
  }
}

// ---------------- batch boundaries (batch is sorted; no atomics) ----------------
__global__ void bounds_k(const int* __restrict__ batch, int* __restrict__ bstart,
                         int* __restrict__ bend, int Nn) {
  int i = blockIdx.x * blockDim.x + threadIdx.x;
  if (i >= Nn) return;
  int b = batch[i];
  if (i == 0 || batch[i - 1] != b) bstart[b] = i;
  if (i == Nn - 1 || batch[i + 1] != b) bend[b] = i + 1;
}

__global__ __launch_bounds__(256) void pool_k(const float* __restrict__ g,
                                              const int* __restrict__ batch,
                                              float* __restrict__ sums, int Nn) {
  int c = blockIdx.x * 256 + threadIdx.x;  // 0..511
  int n0 = blockIdx.y * 50;
  int n1 = min(n0 + 50, Nn);
  if (n0 >= n1) return;
  float acc = 0.f;
  int cur = batch[n0];
  for (int n = n0; n < n1; n++) {
    int b = batch[n];
    if (b != cur) { atomicAdd(&sums[cur * 512 + c], acc); acc = 0.f; cur = b; }
    acc += g[(size_t)n * 512 + c];
  }
  atomicAdd(&sums[cur * 512 + c], acc);
}

// ---------------- mean + fc1(elu) + fc2, one block ----------------
__global__ __launch_bounds__(512) void mlp_k(const float* __restrict__ sums,
                                             const int* __restrict__ bstart,
                                             const int* __restrict__ bend,
                                             const float* __restrict__ w1,
                                             const float* __restrict__ b1,
                                             const float* __restrict__ w2,
                                             const float* __restrict__ b2,
                                             float* __restrict__ out) {
  __shared__ float gm[16 * 512];
  __shared__ float t1[16 * 32];
  int t = threadIdx.x;
  for (int i = t; i < 16 * 512; i += 512) {
    int b = i >> 9;
    float c = (float)(bend[b] - bstart[b]);
    gm[i] = sums[i] / fmaxf(c, 1.f);
  }
  __syncthreads();
  {
    int b = t >> 5, j = t & 31;
    float s = b1[j];
    for (int k = 0; k < 512; k++) s += gm[(b << 9) + k] * w1[k * 32 + j];
    t1[t] = (s > 0.f) ? s : expm1f(s);
  }
  __syncthreads();
  if (t < 160) {
    int b = t / 10, j = t - b * 10;
    float s = b2[j];
#pragma unroll
    for (int k = 0; k < 32; k++) s += t1[b * 32 + k] * w2[k * 10 + j];
    out[t] = s;
  }
}

extern "C" void kernel_launch(void* const* d_in, const int* in_sizes, int n_in,
                              void* d_out, int out_size, void* d_ws, size_t ws_size,
                              hipStream_t stream) {
  const float* x   = (const float*)d_in[0];
  const int*   ei  = (const int*)d_in[1];
  const int* batch = (const int*)d_in[2];
  const float* W1  = (const float*)d_in[3];
  const float* as1 = (const float*)d_in[4];
  const float* ad1 = (const float*)d_in[5];
  const float* b1  = (const float*)d_in[6];
  const float* W2  = (const float*)d_in[7];
  const float* as2 = (const float*)d_in[8];
  const float* ad2 = (const float*)d_in[9];
  const float* b2  = (const float*)d_in[10];
  const float* f1w = (const float*)d_in[11];
  const float* f1b = (const float*)d_in[12];
  const float* f2w = (const float*)d_in[13];
  const float* f2b = (const float*)d_in[14];
  float* out = (float*)d_out;

  const int Nn = in_sizes[2];      // 10000
  const int E = in_sizes[1] / 2;   // 160000
  const int Etot = E + Nn;         // self loops appended

  // ---- workspace layout (4B words, 64-word aligned) ----
  size_t off = 0;
  auto alloc = [&](size_t elems) { size_t o = off; off += (elems + 63) & ~(size_t)63; return o; };
  int* wsi = (int*)d_ws;
  float* wsf = (float*)d_ws;

  size_t o_deg  = alloc(Nn);
  size_t o_pool = alloc(16 * 512);
  size_t o_bst  = alloc(64);
  size_t o_ben  = alloc(64);
  size_t o_as1  = alloc((size_t)Nn * 8);
  size_t o_ad1  = alloc((size_t)Nn * 8);
  size_t o_as2  = alloc((size_t)Nn * 8);
  size_t o_ad2  = alloc((size_t)Nn * 8);
  size_t zero_words = off;               // accumulated-into buffers -> zero each call
  size_t o_offs = alloc(Nn + 1);
  size_t o_cur  = alloc(Nn);
  size_t o_src  = alloc(Etot);
  size_t o_dst  = alloc(Etot);
  size_t o_psrc = alloc(Etot);
  size_t o_pdst = alloc(Etot);
  size_t o_ex   = alloc((size_t)Etot * 8);
  size_t o_xb   = alloc((size_t)Nn * 128 / 2);   // x bf16  [N,128]
  size_t o_w1t  = alloc(1024 * 128 / 2);         // W1^T bf16 [1024,128]
  size_t o_w2t  = alloc(512 * 1024 / 2);         // W2^T bf16 [512,1024]
  size_t o_h    = alloc((size_t)Nn * 1024 / 2);  // h bf16 [N,1024] (layer2 uses first half)
  size_t o_g    = alloc((size_t)Nn * 1024);      // g1 bf16 (first half) then g2 fp32

  ushort_t* xb  = (ushort_t*)(wsi + o_xb);
  ushort_t* w1t = (ushort_t*)(wsi + o_w1t);
  ushort_t* w2t = (ushort_t*)(wsi + o_w2t);
  ushort_t* hb  = (ushort_t*)(wsi + o_h);
  ushort_t* g1b = (ushort_t*)(wsi + o_g);

  int eb = (Etot + 255) / 256;

  zero_k<<<512, 256, 0, stream>>>(wsi, (int)zero_words);
  prep_k<<<eb, 256, 0, stream>>>(ei, wsi + o_src, wsi + o_dst, E, Nn);
  count_k<<<eb, 256, 0, stream>>>(wsi + o_dst, wsi + o_deg, Etot);
  scan_k<<<1, 1024, 0, stream>>>(wsi + o_deg, wsi + o_offs, wsi + o_cur, Nn);
  scatter_k<<<eb, 256, 0, stream>>>(wsi + o_src, wsi + o_dst, wsi + o_cur,
                                    wsi + o_psrc, wsi + o_pdst, Etot);

  // ---- casts for MFMA ----
  cast_k<<<(Nn * 128 / 4 + 255) / 256, 256, 0, stream>>>(x, xb, Nn * 128 / 4);
  tcast_k<<<(128 * 1024 + 255) / 256, 256, 0, stream>>>(W1, w1t, 128, 1024);
  tcast_k<<<(1024 * 512 + 255) / 256, 256, 0, stream>>>(W2, w2t, 1024, 512);

  // ---- layer 1: 128 -> 8x128 ----
  mfma_gemm_k<<<dim3(1024 / 128, (Nn + 127) / 128), 256, 0, stream>>>(
      xb, w1t, hb, as1, ad1, wsf + o_as1, wsf + o_ad1, Nn, 1024, 128, 7);
  edge_k<<<(Etot * 8 + 255) / 256, 256, 0, stream>>>(wsi + o_psrc, wsi + o_pdst,
                                                     wsf + o_as1, wsf + o_ad1, wsf + o_ex, Etot);
  aggregate_k<1024, 7, 256, ushort_t><<<Nn, 256, 0, stream>>>(
      hb, wsf + o_ex, wsi + o_offs, wsi + o_psrc, b1, g1b, Nn);

  // ---- layer 2: 1024 -> 8x64 ----
  mfma_gemm_k<<<dim3(512 / 128, (Nn + 127) / 128), 256, 0, stream>>>(
      g1b, w2t, hb, as2, ad2, wsf + o_as2, wsf + o_ad2, Nn, 512, 1024, 6);
  edge_k<<<(Etot * 8 + 255) / 256, 256, 0, stream>>>(wsi + o_psrc, wsi + o_pdst,
                                                     wsf + o_as2, wsf + o_ad2, wsf + o_ex, Etot);
  aggregate_k<512, 6, 128, float><<<(Nn + 1) / 2, 256, 0, stream>>>(
      hb, wsf + o_ex, wsi + o_offs, wsi + o_psrc, b2, wsf + o_g, Nn);

  // ---- pool + MLP ----
  bounds_k<<<(Nn + 255) / 256, 256, 0, stream>>>(batch, wsi + o_bst, wsi + o_ben, Nn);
  pool_k<<<dim3(2, (Nn + 49) / 50), 256, 0, stream>>>(wsf + o_g, batch, wsf + o_pool, Nn);
  mlp_k<<<1, 512, 0, stream>>>(wsf + o_pool, wsi + o_bst, wsi + o_ben, f1w, f1b, f2w, f2b, out);
}

// Round 7
// 306.942 us; speedup vs baseline: 2.4744x; 1.0785x over previous
//
#include <hip/hip_runtime.h>
#include <math.h>

#define HEADS 8
#define NEG 0.2f

typedef unsigned short ushort_t;
typedef __attribute__((ext_vector_type(8))) short short8;
typedef float f32x4 __attribute__((ext_vector_type(4)));

__device__ inline ushort_t f2bf(float f) {
  union { float f; unsigned u; } v; v.f = f;
  unsigned r = (v.u + 0x7FFF + ((v.u >> 16) & 1)) >> 16;  // RNE
  return (ushort_t)r;
}

__device__ inline float4 bf4(uint2 v) {
  union { unsigned u; float f; } a, b, c, d;
  a.u = v.x << 16; b.u = v.x & 0xffff0000u;
  c.u = v.y << 16; d.u = v.y & 0xffff0000u;
  return make_float4(a.f, b.f, c.f, d.f);
}

// ---------------- utility: zero a word region ----------------
__global__ void zero_k(int* __restrict__ p, int n) {
  int i = blockIdx.x * blockDim.x + threadIdx.x;
  int stride = gridDim.x * blockDim.x;
  for (; i < n; i += stride) p[i] = 0;
}

// ---------------- edge prep: append self loops ----------------
__global__ void prep_k(const int* __restrict__ ei, int* __restrict__ src,
                       int* __restrict__ dst, int E, int Nn) {
  int i = blockIdx.x * blockDim.x + threadIdx.x;
  int tot = E + Nn;
  if (i >= tot) return;
  if (i < E) { src[i] = ei[i]; dst[i] = ei[E + i]; }
  else       { src[i] = i - E; dst[i] = i - E; }
}

__global__ void count_k(const int* __restrict__ dst, int* __restrict__ deg, int Etot) {
  int i = blockIdx.x * blockDim.x + threadIdx.x;
  if (i < Etot) atomicAdd(&deg[dst[i]], 1);
}

// single-block scan over N, wave-shuffle based (2 barriers per 1024-chunk)
__global__ __launch_bounds__(1024) void scan_k(const int* __restrict__ deg,
                                               int* __restrict__ offs,
                                               int* __restrict__ cursor, int Nn) {
  __shared__ int wtot[16];
  __shared__ int wexcl[16];
  __shared__ int soff_s;
  int t = threadIdx.x;
  int lane = t & 63, w = t >> 6;
  if (t == 0) soff_s = 0;
  __syncthreads();
  for (int base = 0; base < Nn; base += 1024) {
    int v = (base + t < Nn) ? deg[base + t] : 0;
    int sc = v;
#pragma unroll
    for (int o = 1; o < 64; o <<= 1) {
      int x = __shfl_up(sc, o);
      if (lane >= o) sc += x;
    }
    if (lane == 63) wtot[w] = sc;
    __syncthreads();
    if (w == 0) {
      int tv = (lane < 16) ? wtot[lane] : 0;
      int ts = tv;
#pragma unroll
      for (int o = 1; o < 16; o <<= 1) {
        int x = __shfl_up(ts, o);
        if (lane >= o) ts += x;
      }
      if (lane < 16) wexcl[lane] = ts - tv;
      if (lane == 15) wtot[15] = ts;  // chunk total
    }
    __syncthreads();
    int soff = soff_s;
    int excl = soff + wexcl[w] + sc - v;
    if (base + t < Nn) { offs[base + t] = excl; cursor[base + t] = excl; }
    int chunk_total = wtot[15];
    __syncthreads();
    if (t == 0) soff_s = soff + chunk_total;
    __syncthreads();
  }
  if (t == 0) offs[Nn] = soff_s;
}

// scatter src values directly into CSR slot order (no perm indirection)
__global__ void scatter_k(const int* __restrict__ src, const int* __restrict__ dst,
                          int* __restrict__ cursor, int* __restrict__ psrc, int Etot) {
  int i = blockIdx.x * blockDim.x + threadIdx.x;
  if (i >= Etot) return;
  int p = atomicAdd(&cursor[dst[i]], 1);
  psrc[p] = src[i];
}

// ---------------- casts ----------------
__global__ void cast_k(const float* __restrict__ in, ushort_t* __restrict__ out, int n4) {
  int i = blockIdx.x * blockDim.x + threadIdx.x;
  if (i >= n4) return;
  float4 v = ((const float4*)in)[i];
  ushort_t o[4] = {f2bf(v.x), f2bf(v.y), f2bf(v.z), f2bf(v.w)};
  *(uint2*)&out[i * 4] = *(uint2*)o;
}

// W [K][N] fp32 -> Wt [N][K] bf16 (coalesced writes)
__global__ void tcast_k(const float* __restrict__ W, ushort_t* __restrict__ Wt, int K, int N) {
  int idx = blockIdx.x * blockDim.x + threadIdx.x;
  if (idx >= K * N) return;
  int n = idx / K, k = idx - n * K;
  Wt[idx] = f2bf(W[(size_t)k * N + n]);
}

// ------- bf16 MFMA GEMM + fused alpha epilogue: Cb[M,N](bf16) = A @ Bt^T -------
// 128x128 tile, 256 threads (4 waves 2x2), BK=32, 16x16x32 MFMA.
#define LDA 40  // padded LDS row stride (bf16 elems)
__global__ __launch_bounds__(256) void mfma_gemm_k(const ushort_t* __restrict__ A,
                                                   const ushort_t* __restrict__ Bt,
                                                   ushort_t* __restrict__ Cb,
                                                   const float* __restrict__ att_s,
                                                   const float* __restrict__ att_d,
                                                   float* __restrict__ asrc,
                                                   float* __restrict__ adst,
                                                   int M, int N, int K, int CSHIFT) {
  __shared__ ushort_t As[128 * LDA];
  __shared__ ushort_t Bs[128 * LDA];
  int tid = threadIdx.x;
  int lane = tid & 63;
  int wave = tid >> 6;
  int wm = (wave >> 1) * 64, wn = (wave & 1) * 64;
  int bm = blockIdx.y * 128, bn = blockIdx.x * 128;
  int lrow = lane & 15, lq = lane >> 4;

  f32x4 acc[4][4];
#pragma unroll
  for (int i = 0; i < 4; i++)
#pragma unroll
    for (int j = 0; j < 4; j++) acc[i][j] = 0.f;

  int srow = tid >> 2;          // 0..63
  int skc = (tid & 3) * 8;      // k elem offset within BK

  for (int k0 = 0; k0 < K; k0 += 32) {
    int gr0 = min(bm + srow, M - 1);
    int gr1 = min(bm + srow + 64, M - 1);
    short8 va0 = *(const short8*)&A[(size_t)gr0 * K + k0 + skc];
    short8 va1 = *(const short8*)&A[(size_t)gr1 * K + k0 + skc];
    short8 vb0 = *(const short8*)&Bt[(size_t)(bn + srow) * K + k0 + skc];
    short8 vb1 = *(const short8*)&Bt[(size_t)(bn + srow + 64) * K + k0 + skc];
    __syncthreads();
    *(short8*)&As[srow * LDA + skc] = va0;
    *(short8*)&As[(srow + 64) * LDA + skc] = va1;
    *(short8*)&Bs[srow * LDA + skc] = vb0;
    *(short8*)&Bs[(srow + 64) * LDA + skc] = vb1;
    __syncthreads();
    short8 af[4], bfr[4];
#pragma unroll
    for (int t = 0; t < 4; t++) {
      af[t]  = *(const short8*)&As[(wm + t * 16 + lrow) * LDA + lq * 8];
      bfr[t] = *(const short8*)&Bs[(wn + t * 16 + lrow) * LDA + lq * 8];
    }
#pragma unroll
    for (int i = 0; i < 4; i++)
#pragma unroll
      for (int j = 0; j < 4; j++)
        acc[i][j] = __builtin_amdgcn_mfma_f32_16x16x32_bf16(af[i], bfr[j], acc[i][j], 0, 0, 0);
  }

  // ---- fused alpha partials (fp32, pre-rounding) ----
  {
    int hh = (bn + wn) >> CSHIFT;
    float avs[4], avd[4];
#pragma unroll
    for (int j = 0; j < 4; j++) {
      int col = bn + wn + j * 16 + lrow;  // att [H][N/H] flat == column index
      avs[j] = att_s[col];
      avd[j] = att_d[col];
    }
#pragma unroll
    for (int i = 0; i < 4; i++) {
#pragma unroll
      for (int r = 0; r < 4; r++) {
        float ps = 0.f, pd = 0.f;
#pragma unroll
        for (int j = 0; j < 4; j++) {
          float v = acc[i][j][r];
          ps += v * avs[j];
          pd += v * avd[j];
        }
#pragma unroll
        for (int o = 1; o < 16; o <<= 1) {
          ps += __shfl_xor(ps, o);
          pd += __shfl_xor(pd, o);
        }
        int row = bm + wm + i * 16 + lq * 4 + r;
        if (lrow == 0 && row < M) {
          atomicAdd(&asrc[row * HEADS + hh], ps);
          atomicAdd(&adst[row * HEADS + hh], pd);
        }
      }
    }
  }

  // ---- bf16 store ----
#pragma unroll
  for (int i = 0; i < 4; i++) {
    int row0 = bm + wm + i * 16 + lq * 4;  // C/D: col=lane&15, row=(lane>>4)*4+reg
#pragma unroll
    for (int j = 0; j < 4; j++) {
      int col = bn + wn + j * 16 + lrow;
#pragma unroll
      for (int r = 0; r < 4; r++) {
        int row = row0 + r;
        if (row < M) Cb[(size_t)row * N + col] = f2bf(acc[i][j][r]);
      }
    }
  }
}

// ---- CSR aggregation: LDS edge staging + fused softmax weights + bias + ELU ----
// One node per block, BT = F/4 threads, thread owns 4 consecutive channels.
// Chunked: stage psrc into LDS, compute w[e][h]=exp(leaky(asrc+adst)) once per
// (edge,head) in LDS, then unroll-4 independent row gathers.
template <int F, int CSHIFT, int BT, typename OT>
__global__ __launch_bounds__(BT) void aggregate_k(const ushort_t* __restrict__ hb,
                                                  const float* __restrict__ asrc,
                                                  const float* __restrict__ adst,
                                                  const int* __restrict__ offs,
                                                  const int* __restrict__ psrc,
                                                  const float* __restrict__ bias,
                                                  OT* __restrict__ out) {
  constexpr int CH = 128;  // edges per chunk
  __shared__ int ls[CH];
  __shared__ float lw[CH][HEADS];
  __shared__ float adn[HEADS];
  int n = blockIdx.x;
  int t = threadIdx.x;
  int c0 = 4 * t;
  int hh = c0 >> CSHIFT;
  if (t < HEADS) adn[t] = adst[n * HEADS + t];
  float4 acc = make_float4(0.f, 0.f, 0.f, 0.f);
  float wsum = 0.f;
  int e0 = offs[n], deg = offs[n + 1] - e0;
  for (int base = 0; base < deg; base += CH) {
    int m = min(CH, deg - base);
    __syncthreads();
    if (t < m) ls[t] = psrc[e0 + base + t];
    __syncthreads();
    for (int idx = t; idx < m * HEADS; idx += BT) {
      int e = idx >> 3, h = idx & 7;
      float v = asrc[ls[e] * HEADS + h] + adn[h];
      v = (v > 0.f) ? v : NEG * v;  // leaky_relu(0.2)
      lw[e][h] = expf(v);           // shift-invariant softmax, |v| small
    }
    __syncthreads();
    int i = 0;
    for (; i + 4 <= m; i += 4) {
      int s0 = ls[i], s1 = ls[i + 1], s2 = ls[i + 2], s3 = ls[i + 3];
      float w0 = lw[i][hh], w1 = lw[i + 1][hh], w2 = lw[i + 2][hh], w3 = lw[i + 3][hh];
      uint2 r0 = *(const uint2*)&hb[(size_t)s0 * F + c0];
      uint2 r1 = *(const uint2*)&hb[(size_t)s1 * F + c0];
      uint2 r2 = *(const uint2*)&hb[(size_t)s2 * F + c0];
      uint2 r3 = *(const uint2*)&hb[(size_t)s3 * F + c0];
      float4 f0 = bf4(r0), f1 = bf4(r1), f2 = bf4(r2), f3 = bf4(r3);
      wsum += (w0 + w1) + (w2 + w3);
      acc.x += w0 * f0.x + w1 * f1.x + w2 * f2.x + w3 * f3.x;
      acc.y += w0 * f0.y + w1 * f1.y + w2 * f2.y + w3 * f3.y;
      acc.z += w0 * f0.z + w1 * f1.z + w2 * f2.z + w3 * f3.z;
      acc.w += w0 * f0.w + w1 * f1.w + w2 * f2.w + w3 * f3.w;
    }
    for (; i < m; i++) {
      int s0 = ls[i];
      float w0 = lw[i][hh];
      float4 f0 = bf4(*(const uint2*)&hb[(size_t)s0 * F + c0]);
      wsum += w0;
      acc.x += w0 * f0.x; acc.y += w0 * f0.y;
      acc.z += w0 * f0.z; acc.w += w0 * f0.w;
    }
  }
  float inv = 1.f / wsum;
  float v0 = acc.x * inv + bias[c0];
  float v1 = acc.y * inv + bias[c0 + 1];
  float v2 = acc.z * inv + bias[c0 + 2];
  float v3 = acc.w * inv + bias[c0 + 3];
  v0 = (v0 > 0.f) ? v0 : expm1f(v0);
  v1 = (v1 > 0.f) ? v1 : expm1f(v1);
  v2 = (v2 > 0.f) ? v2 : expm1f(v2);
  v3 = (v3 > 0.f) ? v3 : expm1f(v3);
  if (sizeof(OT) == 2) {
    unsigned p0 = (unsigned)f2bf(v0) | ((unsigned)f2bf(v1) << 16);
    unsigned p1 = (unsigned)f2bf(v2) | ((unsigned)f2bf(v3) << 16);
    *(uint2*)&((ushort_t*)out)[(size_t)n * F + c0] = make_uint2(p0, p1);
  } else {
    *(float4*)&((float*)out)[(size_t)n * F + c0] = make_float4(v0, v1, v2, v3);
  }
}

// ---------------- batch boundaries (batch is sorted; no atomics) ----------------
__global__ void bounds_k(const int* __restrict__ batch, int* __restrict__ bstart,
                         int* __restrict__ bend, int Nn) {
  int i = blockIdx.x * blockDim.x + threadIdx.x;
  if (i >= Nn) return;
  int b = batch[i];
  if (i == 0 || batch[i - 1] != b) bstart[b] = i;
  if (i == Nn - 1 || batch[i + 1] != b) bend[b] = i + 1;
}

__global__ __launch_bounds__(256) void pool_k(const float* __restrict__ g,
                                              const int* __restrict__ batch,
                                              float* __restrict__ sums, int Nn) {
  int c = blockIdx.x * 256 + threadIdx.x;  // 0..511
  int n0 = blockIdx.y * 50;
  int n1 = min(n0 + 50, Nn);
  if (n0 >= n1) return;
  float acc = 0.f;
  int cur = batch[n0];
  for (int n = n0; n < n1; n++) {
    int b = batch[n];
    if (b != cur) { atomicAdd(&sums[cur * 512 + c], acc); acc = 0.f; cur = b; }
    acc += g[(size_t)n * 512 + c];
  }
  atomicAdd(&sums[cur * 512 + c], acc);
}

// ---------------- mean + fc1(elu) + fc2, one block ----------------
__global__ __launch_bounds__(512) void mlp_k(const float* __restrict__ sums,
                                             const int* __restrict__ bstart,
                                             const int* __restrict__ bend,
                                             const float* __restrict__ w1,
                                             const float* __restrict__ b1,
                                             const float* __restrict__ w2,
                                             const float* __restrict__ b2,
                                             float* __restrict__ out) {
  __shared__ float gm[16 * 512];
  __shared__ float t1[16 * 32];
  int t = threadIdx.x;
  for (int i = t; i < 16 * 512; i += 512) {
    int b = i >> 9;
    float c = (float)(bend[b] - bstart[b]);
    gm[i] = sums[i] / fmaxf(c, 1.f);
  }
  __syncthreads();
  {
    int b = t >> 5, j = t & 31;
    float s = b1[j];
    for (int k = 0; k < 512; k++) s += gm[(b << 9) + k] * w1[k * 32 + j];
    t1[t] = (s > 0.f) ? s : expm1f(s);
  }
  __syncthreads();
  if (t < 160) {
    int b = t / 10, j = t - b * 10;
    float s = b2[j];
#pragma unroll
    for (int k = 0; k < 32; k++) s += t1[b * 32 + k] * w2[k * 10 + j];
    out[t] = s;
  }
}

extern "C" void kernel_launch(void* const* d_in, const int* in_sizes, int n_in,
                              void* d_out, int out_size, void* d_ws, size_t ws_size,
                              hipStream_t stream) {
  const float* x   = (const float*)d_in[0];
  const int*   ei  = (const int*)d_in[1];
  const int* batch = (const int*)d_in[2];
  const float* W1  = (const float*)d_in[3];
  const float* as1 = (const float*)d_in[4];
  const float* ad1 = (const float*)d_in[5];
  const float* b1  = (const float*)d_in[6];
  const float* W2  = (const float*)d_in[7];
  const float* as2 = (const float*)d_in[8];
  const float* ad2 = (const float*)d_in[9];
  const float* b2  = (const float*)d_in[10];
  const float* f1w = (const float*)d_in[11];
  const float* f1b = (const float*)d_in[12];
  const float* f2w = (const float*)d_in[13];
  const float* f2b = (const float*)d_in[14];
  float* out = (float*)d_out;

  const int Nn = in_sizes[2];      // 10000
  const int E = in_sizes[1] / 2;   // 160000
  const int Etot = E + Nn;         // self loops appended

  // ---- workspace layout (4B words, 64-word aligned) ----
  size_t off = 0;
  auto alloc = [&](size_t elems) { size_t o = off; off += (elems + 63) & ~(size_t)63; return o; };
  int* wsi = (int*)d_ws;
  float* wsf = (float*)d_ws;

  size_t o_deg  = alloc(Nn);
  size_t o_pool = alloc(16 * 512);
  size_t o_bst  = alloc(64);
  size_t o_ben  = alloc(64);
  size_t o_as1  = alloc((size_t)Nn * 8);
  size_t o_ad1  = alloc((size_t)Nn * 8);
  size_t o_as2  = alloc((size_t)Nn * 8);
  size_t o_ad2  = alloc((size_t)Nn * 8);
  size_t zero_words = off;               // accumulated-into buffers -> zero each call
  size_t o_offs = alloc(Nn + 1);
  size_t o_cur  = alloc(Nn);
  size_t o_src  = alloc(Etot);
  size_t o_dst  = alloc(Etot);
  size_t o_psrc = alloc(Etot);
  size_t o_xb   = alloc((size_t)Nn * 128 / 2);   // x bf16  [N,128]
  size_t o_w1t  = alloc(1024 * 128 / 2);         // W1^T bf16 [1024,128]
  size_t o_w2t  = alloc(512 * 1024 / 2);         // W2^T bf16 [512,1024]
  size_t o_h    = alloc((size_t)Nn * 1024 / 2);  // h bf16 [N,1024] (layer2 uses first half)
  size_t o_g    = alloc((size_t)Nn * 1024);      // g1 bf16 (first half) then g2 fp32

  ushort_t* xb  = (ushort_t*)(wsi + o_xb);
  ushort_t* w1t = (ushort_t*)(wsi + o_w1t);
  ushort_t* w2t = (ushort_t*)(wsi + o_w2t);
  ushort_t* hb  = (ushort_t*)(wsi + o_h);
  ushort_t* g1b = (ushort_t*)(wsi + o_g);

  int eb = (Etot + 255) / 256;

  zero_k<<<512, 256, 0, stream>>>(wsi, (int)zero_words);
  prep_k<<<eb, 256, 0, stream>>>(ei, wsi + o_src, wsi + o_dst, E, Nn);
  count_k<<<eb, 256, 0, stream>>>(wsi + o_dst, wsi + o_deg, Etot);
  scan_k<<<1, 1024, 0, stream>>>(wsi + o_deg, wsi + o_offs, wsi + o_cur, Nn);
  scatter_k<<<eb, 256, 0, stream>>>(wsi + o_src, wsi + o_dst, wsi + o_cur,
                                    wsi + o_psrc, Etot);

  // ---- casts for MFMA ----
  cast_k<<<(Nn * 128 / 4 + 255) / 256, 256, 0, stream>>>(x, xb, Nn * 128 / 4);
  tcast_k<<<(128 * 1024 + 255) / 256, 256, 0, stream>>>(W1, w1t, 128, 1024);
  tcast_k<<<(1024 * 512 + 255) / 256, 256, 0, stream>>>(W2, w2t, 1024, 512);

  // ---- layer 1: 128 -> 8x128 ----
  mfma_gemm_k<<<dim3(1024 / 128, (Nn + 127) / 128), 256, 0, stream>>>(
      xb, w1t, hb, as1, ad1, wsf + o_as1, wsf + o_ad1, Nn, 1024, 128, 7);
  aggregate_k<1024, 7, 256, ushort_t><<<Nn, 256, 0, stream>>>(
      hb, wsf + o_as1, wsf + o_ad1, wsi + o_offs, wsi + o_psrc, b1, g1b);

  // ---- layer 2: 1024 -> 8x64 ----
  mfma_gemm_k<<<dim3(512 / 128, (Nn + 127) / 128), 256, 0, stream>>>(
      g1b, w2t, hb, as2, ad2, wsf + o_as2, wsf + o_ad2, Nn, 512, 1024, 6);
  aggregate_k<512, 6, 128, float><<<Nn, 128, 0, stream>>>(
      hb, wsf + o_as2, wsf + o_ad2, wsi + o_offs, wsi + o_psrc, b2, wsf + o_g);

  // ---- pool + MLP ----
  bounds_k<<<(Nn + 255) / 256, 256, 0, stream>>>(batch, wsi + o_bst, wsi + o_ben, Nn);
  pool_k<<<dim3(2, (Nn + 49) / 50), 256, 0, stream>>>(wsf + o_g, batch, wsf + o_pool, Nn);
  mlp_k<<<1, 512, 0, stream>>>(wsf + o_pool, wsi + o_bst, wsi + o_ben, f1w, f1b, f2w, f2b, out);
}